// Round 6
// baseline (415.572 us; speedup 1.0000x reference)
//
#include <hip/hip_runtime.h>
#include <hip/hip_bf16.h>
#include <math.h>

#define BB 64
#define NN 16
#define HH 100
#define DD 400
#define AA 200
#define CATN 19
#define NODES 118            // HH + CATN-1
#define BN (BB*NODES)        // 7552
#define BH (BB*HH)           // 6400
#define ATT_INV 0.07071067811865475f   // 1/sqrt(200)

typedef __attribute__((ext_vector_type(4))) float f32x4;
typedef __attribute__((ext_vector_type(8))) short s16x8;

__device__ __forceinline__ unsigned short f2bf(float f) {
  union { float f; unsigned int u; } v; v.f = f;
  unsigned int r = v.u + 0x7FFFu + ((v.u >> 16) & 1u);
  return (unsigned short)(r >> 16);
}
__device__ __forceinline__ float bf2f(unsigned short u) {
  union { unsigned int i; float f; } v; v.i = ((unsigned int)u) << 16; return v.f;
}

// ---------------------------------------------------------------- concat he
__global__ __launch_bounds__(256) void k_concat_he(const float* __restrict__ hist,
    const float* __restrict__ proxy, float* __restrict__ he, int total) {
  int idx = blockIdx.x * 256 + threadIdx.x;
  if (idx >= total) return;
  int d = idx % DD;
  int bi = idx / DD;
  int i = bi % NODES;
  int b = bi / NODES;
  he[idx] = (i < HH) ? hist[((size_t)b * HH + i) * DD + d] : proxy[(size_t)(i - HH) * DD + d];
}

// ---------------- transpose h[b][RPB][400] fp32 -> T[b][416][128] bf16 (j-padded)
template<int RPB>
__global__ __launch_bounds__(256) void k_toT(const float* __restrict__ h,
    unsigned short* __restrict__ T) {
  __shared__ float t_sh[64][129];
  const int b = blockIdx.x / 7, dt = blockIdx.x % 7;
  const int d0 = dt * 64;
  const int tid = threadIdx.x;
  const int dc = tid & 63, jr = tid >> 6;
  for (int j0 = 0; j0 < 128; j0 += 4) {
    int j = j0 + jr, d = d0 + dc;
    float v = (j < RPB && d < DD) ? h[((size_t)b * RPB + j) * DD + d] : 0.f;
    t_sh[dc][j] = v;
  }
  __syncthreads();
  const int jc = tid & 127, dr2 = tid >> 7;
  for (int di = 0; di < 64; di += 2) {
    int dr = di + dr2;
    int d = d0 + dr;
    if (d < 416) T[((size_t)b * 416 + d) * 128 + jc] = f2bf(t_sh[dr][jc]);
  }
}

// ---------------- graph MFMA: tmpb[b][i][0..415] = bf16( G[b] @ h[b] )
__global__ __launch_bounds__(256) void k_gmm(const float* __restrict__ G,
    const unsigned short* __restrict__ hT, unsigned short* __restrict__ tmpb) {
  __shared__ unsigned short a_sh[32 * 136];
  const int b = blockIdx.x >> 2;
  const int i0 = (blockIdx.x & 3) * 32;
  const int tid = threadIdx.x;
  for (int idx = tid; idx < 32 * 128; idx += 256) {
    int r = idx >> 7, j = idx & 127;
    int i = i0 + r;
    float v = (i < NODES && j < NODES) ? G[((size_t)b * NODES + i) * NODES + j] : 0.f;
    a_sh[r * 136 + j] = f2bf(v);
  }
  __syncthreads();
  const int lane = tid & 63, w = tid >> 6;
  const int lrow = lane & 15, lk = lane >> 4;
  const int rg = w & 1, nh = w >> 1;
  const int cbeg = nh * 13;
  f32x4 acc[13];
#pragma unroll
  for (int c = 0; c < 13; ++c) acc[c] = f32x4{0.f, 0.f, 0.f, 0.f};
  const unsigned short* ap = &a_sh[(rg * 16 + lrow) * 136 + lk * 8];
  const unsigned short* wp = &hT[((size_t)b * 416 + cbeg * 16 + lrow) * 128 + lk * 8];
  for (int ks = 0; ks < 4; ++ks) {
    s16x8 af = *reinterpret_cast<const s16x8*>(ap + ks * 32);
#pragma unroll
    for (int c = 0; c < 13; ++c) {
      s16x8 bf = *reinterpret_cast<const s16x8*>(wp + (size_t)c * 16 * 128 + ks * 32);
      acc[c] = __builtin_amdgcn_mfma_f32_16x16x32_bf16(af, bf, acc[c], 0, 0, 0);
    }
  }
  const int r0 = rg * 16 + lk * 4;
#pragma unroll
  for (int c = 0; c < 13; ++c) {
    int col = (cbeg + c) * 16 + lrow;
#pragma unroll
    for (int j = 0; j < 4; ++j) {
      int i = i0 + r0 + j;
      if (i < NODES)
        tmpb[((size_t)b * NODES + i) * 416 + col] = f2bf(acc[c][j]);
    }
  }
}

// ---------------- dense LN GEMM, bf16 A direct-global: out = LN(relu(A@W+b)+resid)
__global__ __launch_bounds__(256) void k_mgb_ln(
    const unsigned short* __restrict__ A, const unsigned short* __restrict__ Wt,
    const float* __restrict__ bias, const float* __restrict__ resid,
    const float* __restrict__ lns, const float* __restrict__ lnb,
    float* __restrict__ out) {
  __shared__ float ps_sh[32][2][2];
  const int tid = threadIdx.x;
  const size_t row0 = (size_t)blockIdx.x * 32;
  const int lane = tid & 63, w = tid >> 6;
  const int lrow = lane & 15, lk = lane >> 4;
  const int rg = w & 1, nh = w >> 1;
  const int cbeg = nh * 13;
  f32x4 acc[13];
#pragma unroll
  for (int c = 0; c < 13; ++c) acc[c] = f32x4{0.f, 0.f, 0.f, 0.f};
  const unsigned short* ap = &A[(row0 + rg * 16 + lrow) * 416 + lk * 8];
  const unsigned short* wp = &Wt[((size_t)(cbeg * 16) + lrow) * 416 + lk * 8];
  for (int ks = 0; ks < 13; ++ks) {
    s16x8 af = *reinterpret_cast<const s16x8*>(ap + ks * 32);
#pragma unroll
    for (int c = 0; c < 13; ++c) {
      s16x8 bf = *reinterpret_cast<const s16x8*>(wp + (size_t)c * 16 * 416 + ks * 32);
      acc[c] = __builtin_amdgcn_mfma_f32_16x16x32_bf16(af, bf, acc[c], 0, 0, 0);
    }
  }
  const int r0 = rg * 16 + lk * 4;
  float zs[4], zq[4];
#pragma unroll
  for (int j = 0; j < 4; ++j) { zs[j] = 0.f; zq[j] = 0.f; }
#pragma unroll
  for (int c = 0; c < 13; ++c) {
    int col = (cbeg + c) * 16 + lrow;
    bool cv = col < DD;
    float bv = cv ? bias[col] : 0.f;
#pragma unroll
    for (int j = 0; j < 4; ++j) {
      float z = 0.f;
      if (cv)
        z = fmaxf(acc[c][j] + bv, 0.f) + resid[(row0 + r0 + j) * (size_t)DD + col];
      acc[c][j] = z;
      zs[j] += z;
      zq[j] += z * z;
    }
  }
#pragma unroll
  for (int j = 0; j < 4; ++j) {
    zs[j] += __shfl_xor(zs[j], 1, 64); zq[j] += __shfl_xor(zq[j], 1, 64);
    zs[j] += __shfl_xor(zs[j], 2, 64); zq[j] += __shfl_xor(zq[j], 2, 64);
    zs[j] += __shfl_xor(zs[j], 4, 64); zq[j] += __shfl_xor(zq[j], 4, 64);
    zs[j] += __shfl_xor(zs[j], 8, 64); zq[j] += __shfl_xor(zq[j], 8, 64);
  }
  if (lrow == 0) {
#pragma unroll
    for (int j = 0; j < 4; ++j) {
      ps_sh[r0 + j][nh][0] = zs[j];
      ps_sh[r0 + j][nh][1] = zq[j];
    }
  }
  __syncthreads();
  float mu[4], rs[4];
#pragma unroll
  for (int j = 0; j < 4; ++j) {
    float s = ps_sh[r0 + j][0][0] + ps_sh[r0 + j][1][0];
    float q = ps_sh[r0 + j][0][1] + ps_sh[r0 + j][1][1];
    mu[j] = s * (1.0f / DD);
    float var = q * (1.0f / DD) - mu[j] * mu[j];
    rs[j] = 1.0f / sqrtf(var + 1e-5f);
  }
#pragma unroll
  for (int c = 0; c < 13; ++c) {
    int col = (cbeg + c) * 16 + lrow;
    if (col < DD) {
      float sc = lns[col], bo = lnb[col];
#pragma unroll
      for (int j = 0; j < 4; ++j)
        out[(row0 + r0 + j) * (size_t)DD + col] = (acc[c][j] - mu[j]) * rs[j] * sc + bo;
    }
  }
}

// ------------------------------- gf[b*100+i] = h2[b*118+i] + he[b*118+i]  (compact)
__global__ __launch_bounds__(256) void k_add_gf(const float* __restrict__ h2,
    const float* __restrict__ he, float* __restrict__ gf, int total) {
  int idx = blockIdx.x * 256 + threadIdx.x;
  if (idx >= total) return;
  int d = idx % DD;
  int bi = idx / DD;
  int i = bi % HH;
  int b = bi / HH;
  size_t src = ((size_t)b * NODES + i) * DD + d;
  gf[idx] = h2[src] + he[src];
}

// ---------------- one-shot weight prep (bf16 transposed+padded blobs)
// blob map (ushort offsets into wbase):
//   gW0t @0        [416][416]
//   gW1t @173056   [416][416]
//   afWt @346112   [416][416]
//   Kwt  @519168   [224][416]
//   icKwB@612352   [416][224]  (row d = icKw[d,:])
//   icQwB@705536   [416][224]  (row k = icQw[k,:])
//   Wqp  @798720   [608][416]  (rows 0..207 = Qw cols; rows 208.. filled by k_prep_M)
// bias3 float[608]: 0..199 Qb ; 208..607 pb[d] = icQb . icKw[d,:]
__global__ __launch_bounds__(256) void k_prep_all(const float* __restrict__ gW,
    const float* __restrict__ afW, const float* __restrict__ Kw,
    const float* __restrict__ Qw, const float* __restrict__ icQw,
    const float* __restrict__ icKw, const float* __restrict__ Qb,
    const float* __restrict__ icQb, unsigned short* __restrict__ wbase,
    float* __restrict__ bias3) {
  int idx = blockIdx.x * 256 + threadIdx.x;
  const int SG = 416 * 416;   // 173056
  const int SK = 224 * 416;   // 93184
  if (idx < SG) {             // gW0t
    int n = idx / 416, k = idx - n * 416;
    wbase[idx] = (n < 400 && k < 400) ? f2bf(gW[(size_t)k * 400 + n]) : (unsigned short)0;
    return;
  }
  idx -= SG;
  if (idx < SG) {             // gW1t
    int n = idx / 416, k = idx - n * 416;
    wbase[173056 + idx] = (n < 400 && k < 400) ? f2bf(gW[160000 + (size_t)k * 400 + n]) : (unsigned short)0;
    return;
  }
  idx -= SG;
  if (idx < SG) {             // afWt
    int n = idx / 416, k = idx - n * 416;
    wbase[346112 + idx] = (n < 400 && k < 400) ? f2bf(afW[(size_t)k * 400 + n]) : (unsigned short)0;
    return;
  }
  idx -= SG;
  if (idx < SK) {             // Kwt [224 n][416 k]
    int n = idx / 416, k = idx - n * 416;
    wbase[519168 + idx] = (n < 200 && k < 400) ? f2bf(Kw[(size_t)k * 200 + n]) : (unsigned short)0;
    return;
  }
  idx -= SK;
  if (idx < SK) {             // icKwB [416 d][224 a]
    int d = idx / 224, a = idx - d * 224;
    wbase[612352 + idx] = (d < 400 && a < 200) ? f2bf(icKw[(size_t)d * 200 + a]) : (unsigned short)0;
    return;
  }
  idx -= SK;
  if (idx < SK) {             // icQwB [416 k][224 a]
    int k = idx / 224, a = idx - k * 224;
    wbase[705536 + idx] = (k < 400 && a < 200) ? f2bf(icQw[(size_t)k * 200 + a]) : (unsigned short)0;
    return;
  }
  idx -= SK;
  if (idx < 208 * 416) {      // Wqp rows 0..207 (Q part)
    int n = idx / 416, k = idx - n * 416;
    wbase[798720 + idx] = (n < 200 && k < 400) ? f2bf(Qw[(size_t)k * 200 + n]) : (unsigned short)0;
    return;
  }
  idx -= 208 * 416;
  if (idx < 608) {            // bias3
    float v = 0.f;
    if (idx < 200) v = Qb[idx];
    else if (idx >= 208) {
      const float* kr = icKw + (size_t)(idx - 208) * 200;
      float s = 0.f;
      for (int a = 0; a < 200; ++a) s += icQb[a] * kr[a];
      v = s;
    }
    bias3[idx] = v;
  }
}

// ---------------- M-prep: Wqp[208+d][k] = bf16( sum_a icKw[d,a]*icQw[k,a] ), MFMA
__global__ __launch_bounds__(256) void k_prep_M(const unsigned short* __restrict__ icKwB,
    const unsigned short* __restrict__ icQwB, unsigned short* __restrict__ wqp) {
  const int tid = threadIdx.x;
  const size_t row0 = (size_t)blockIdx.x * 32;
  const int lane = tid & 63, w = tid >> 6;
  const int lrow = lane & 15, lk = lane >> 4;
  const int rg = w & 1, nh = w >> 1;
  const int cbeg = nh * 13;
  f32x4 acc[13];
#pragma unroll
  for (int c = 0; c < 13; ++c) acc[c] = f32x4{0.f, 0.f, 0.f, 0.f};
  const unsigned short* ap = &icKwB[(row0 + rg * 16 + lrow) * 224 + lk * 8];
  const unsigned short* bp = &icQwB[((size_t)(cbeg * 16) + lrow) * 224 + lk * 8];
  for (int ks = 0; ks < 7; ++ks) {
    s16x8 af = *reinterpret_cast<const s16x8*>(ap + ks * 32);
#pragma unroll
    for (int c = 0; c < 13; ++c) {
      s16x8 bf = *reinterpret_cast<const s16x8*>(bp + (size_t)c * 16 * 224 + ks * 32);
      acc[c] = __builtin_amdgcn_mfma_f32_16x16x32_bf16(af, bf, acc[c], 0, 0, 0);
    }
  }
  const int r0 = rg * 16 + lk * 4;
#pragma unroll
  for (int c = 0; c < 13; ++c) {
    int k = (cbeg + c) * 16 + lrow;
#pragma unroll
    for (int j = 0; j < 4; ++j) {
      size_t d = row0 + r0 + j;
      if (d < 400) wqp[(208 + d) * 416 + k] = f2bf(acc[c][j]);
    }
  }
}

// =================== fp32-A MFMA GEMM. EPI: 0 plain(colguard), 6 QP dual-output
template<int KDIM, int KPAD, int NOUT, int EPI>
__global__ __launch_bounds__(256) void k_mg(
    const float* __restrict__ A, const unsigned short* __restrict__ Wt,
    const float* __restrict__ bias, float* __restrict__ out, float* __restrict__ out2) {
  constexpr int APITCH = KPAD + 8;
  constexpr int NF = (NOUT + 15) / 16;
  constexpr int NF0 = (NF + 1) / 2;
  constexpr int KS = KPAD / 32;
  constexpr int E4 = KDIM / 4;
  constexpr int PADN = KPAD - KDIM;
  __shared__ unsigned short a_sh[32 * APITCH];
  const int tid = threadIdx.x;
  const size_t row0 = (size_t)blockIdx.x * 32;
  for (int i = tid; i < 32 * E4; i += 256) {
    int r = i / E4, c4 = i - r * E4;
    const float4 v = *reinterpret_cast<const float4*>(&A[(row0 + r) * (size_t)KDIM + c4 * 4]);
    unsigned int lo = (unsigned int)f2bf(v.x) | ((unsigned int)f2bf(v.y) << 16);
    unsigned int hi = (unsigned int)f2bf(v.z) | ((unsigned int)f2bf(v.w) << 16);
    *reinterpret_cast<uint2*>(&a_sh[r * APITCH + c4 * 4]) = make_uint2(lo, hi);
  }
  for (int i = tid; i < 32 * PADN; i += 256) {
    int r = i / PADN, c = i - r * PADN;
    a_sh[r * APITCH + KDIM + c] = 0;
  }
  __syncthreads();
  const int lane = tid & 63, w = tid >> 6;
  const int lrow = lane & 15, lk = lane >> 4;
  const int rg = w & 1, nh = w >> 1;
  const int cbeg = nh * NF0;
  f32x4 acc[NF0];
#pragma unroll
  for (int c = 0; c < NF0; ++c) acc[c] = f32x4{0.f, 0.f, 0.f, 0.f};
  const unsigned short* ap = &a_sh[(rg * 16 + lrow) * APITCH + lk * 8];
  const unsigned short* wp = &Wt[((size_t)(cbeg * 16) + lrow) * KPAD + lk * 8];
  for (int ks = 0; ks < KS; ++ks) {
    s16x8 af = *reinterpret_cast<const s16x8*>(ap + ks * 32);
#pragma unroll
    for (int c = 0; c < NF0; ++c) {
      s16x8 bf = *reinterpret_cast<const s16x8*>(wp + (size_t)c * 16 * KPAD + ks * 32);
      acc[c] = __builtin_amdgcn_mfma_f32_16x16x32_bf16(af, bf, acc[c], 0, 0, 0);
    }
  }
  const int r0 = rg * 16 + lk * 4;
  if (EPI == 0) {
#pragma unroll
    for (int c = 0; c < NF0; ++c) {
      int col = (cbeg + c) * 16 + lrow;
      if (col < NOUT) {
#pragma unroll
        for (int j = 0; j < 4; ++j)
          out[(row0 + r0 + j) * (size_t)NOUT + col] = acc[c][j];
      }
    }
  } else {  // EPI == 6: col<200 -> out[.,col]+b ; 208<=col<608 -> out2[.,col-208]+b
#pragma unroll
    for (int c = 0; c < NF0; ++c) {
      int col = (cbeg + c) * 16 + lrow;
      if (col < 200) {
        float bv = bias[col];
#pragma unroll
        for (int j = 0; j < 4; ++j)
          out[(row0 + r0 + j) * (size_t)AA + col] = acc[c][j] + bv;
      } else if (col >= 208 && col < 608) {
        float bv = bias[col];
#pragma unroll
        for (int j = 0; j < 4; ++j)
          out2[(row0 + r0 + j) * (size_t)DD + (col - 208)] = acc[c][j] + bv;
      }
    }
  }
}

// --------- alpha segment-softmax -> P bf16 [b][320 pitch][128]
__global__ __launch_bounds__(256) void k_palpha(const float* __restrict__ K,
    const float* __restrict__ Q, const int* __restrict__ cat,
    unsigned short* __restrict__ P) {
  __shared__ float q_sh[AA];
  __shared__ float a_sh[HH];
  __shared__ int c_sh[HH];
  __shared__ float smax[CATN], sden[CATN];
  const int bn = blockIdx.x;
  const int b = bn >> 4, n = bn & 15;
  const int tid = threadIdx.x;
  if (tid < AA) q_sh[tid] = Q[(size_t)bn * AA + tid];
  if (tid < HH) c_sh[tid] = cat[b * HH + tid];
  __syncthreads();
  if (tid < 2 * HH) {
    int h = tid >> 1, half = tid & 1;
    const float* kp = K + ((size_t)b * HH + h) * AA + half * 100;
    const float* qp = q_sh + half * 100;
    float s = 0.f;
#pragma unroll 4
    for (int a = 0; a < 100; ++a) s += kp[a] * qp[a];
    s += __shfl_xor(s, 1, 64);
    if (half == 0) a_sh[h] = s * ATT_INV;
  }
  __syncthreads();
  if (tid < CATN) {
    float m = -3.4e38f;
    for (int h = 0; h < HH; ++h)
      if (c_sh[h] == tid) m = fmaxf(m, a_sh[h]);
    smax[tid] = m;
  }
  __syncthreads();
  if (tid < HH) a_sh[tid] = expf(a_sh[tid] - smax[c_sh[tid]]);
  __syncthreads();
  if (tid < CATN) {
    float dsum = 0.f;
    for (int h = 0; h < HH; ++h)
      if (c_sh[h] == tid) dsum += a_sh[h];
    sden[tid] = dsum;
  }
  __syncthreads();
  if (tid < HH) a_sh[tid] = a_sh[tid] / sden[c_sh[tid]];
  __syncthreads();
  for (int idx = tid; idx < CATN * 128; idx += 256) {
    int c = idx >> 7, h = idx & 127;
    float v = (h < HH && c_sh[h] == c) ? a_sh[h] : 0.f;
    P[((size_t)b * 320 + n * CATN + c) * 128 + h] = f2bf(v);
  }
}

// --------- fused intra phase: block per (b,n).
// GEMM1 intra = P@gfT (M=32,K=128) -> LDS bf16 (rows >= CATN zeroed!) ->
// GEMM2 affine (K=416) -> v = relu(+afb)+resid ; s = v.p ; masked softmax(19) ;
// out = sum_c w*v
__global__ __launch_bounds__(256) void k_intra(
    const unsigned short* __restrict__ P, const unsigned short* __restrict__ gfT,
    const unsigned short* __restrict__ afWt, const float* __restrict__ afb,
    const float* __restrict__ pbuf, const int* __restrict__ mask,
    float* __restrict__ out) {
  __shared__ unsigned short a_sh[32 * 424];
  __shared__ float p_sh[DD];
  __shared__ float ps_sh[32][2];
  __shared__ float w_sh[32];
  __shared__ float osum[2][DD];
  const int bn = blockIdx.x, b = bn >> 4, n = bn & 15;
  const int tid = threadIdx.x;
  for (int i = tid; i < DD; i += 256) p_sh[i] = pbuf[(size_t)bn * DD + i];
  const int lane = tid & 63, w = tid >> 6;
  const int lrow = lane & 15, lk = lane >> 4;
  const int rg = w & 1, nh = w >> 1;
  const int cbeg = nh * 13;
  const int r0 = rg * 16 + lk * 4;
  // --- GEMM1 ---
  f32x4 acc[13];
#pragma unroll
  for (int c = 0; c < 13; ++c) acc[c] = f32x4{0.f, 0.f, 0.f, 0.f};
  {
    const unsigned short* ap = &P[((size_t)b * 320 + n * CATN + rg * 16 + lrow) * 128 + lk * 8];
    const unsigned short* bp = &gfT[((size_t)b * 416 + cbeg * 16 + lrow) * 128 + lk * 8];
    for (int ks = 0; ks < 4; ++ks) {
      s16x8 af = *reinterpret_cast<const s16x8*>(ap + ks * 32);
#pragma unroll
      for (int c = 0; c < 13; ++c) {
        s16x8 bf = *reinterpret_cast<const s16x8*>(bp + (size_t)c * 16 * 128 + ks * 32);
        acc[c] = __builtin_amdgcn_mfma_f32_16x16x32_bf16(af, bf, acc[c], 0, 0, 0);
      }
    }
  }
  // stage intra tile (bf16) -> a_sh. CRITICAL: rows >= CATN come from garbage
  // P rows (esp. n==15 where P rows 304..319 are never written) -> zero them so
  // no NaN/Inf reaches GEMM2 / the 0-weighted epilogue sums.
#pragma unroll
  for (int c = 0; c < 13; ++c) {
    int col = (cbeg + c) * 16 + lrow;
#pragma unroll
    for (int j = 0; j < 4; ++j)
      a_sh[(r0 + j) * 424 + col] = f2bf((r0 + j) < CATN ? acc[c][j] : 0.f);
  }
  __syncthreads();
  // --- GEMM2 ---
  f32x4 acc2[13];
#pragma unroll
  for (int c = 0; c < 13; ++c) acc2[c] = f32x4{0.f, 0.f, 0.f, 0.f};
  {
    const unsigned short* ap = &a_sh[(rg * 16 + lrow) * 424 + lk * 8];
    const unsigned short* bp = &afWt[((size_t)(cbeg * 16) + lrow) * 416 + lk * 8];
    for (int ks = 0; ks < 13; ++ks) {
      s16x8 af = *reinterpret_cast<const s16x8*>(ap + ks * 32);
#pragma unroll
      for (int c = 0; c < 13; ++c) {
        s16x8 bf = *reinterpret_cast<const s16x8*>(bp + (size_t)c * 16 * 416 + ks * 32);
        acc2[c] = __builtin_amdgcn_mfma_f32_16x16x32_bf16(af, bf, acc2[c], 0, 0, 0);
      }
    }
  }
  // --- s-dot ---
  float spart[4] = {0.f, 0.f, 0.f, 0.f};
#pragma unroll
  for (int c = 0; c < 13; ++c) {
    int col = (cbeg + c) * 16 + lrow;
    if (col < DD) {
      float bv = afb[col], pv = p_sh[col];
#pragma unroll
      for (int j = 0; j < 4; ++j) {
        float v = fmaxf(acc2[c][j] + bv, 0.f) + bf2f(a_sh[(r0 + j) * 424 + col]);
        spart[j] += v * pv;
      }
    }
  }
#pragma unroll
  for (int j = 0; j < 4; ++j) {
    spart[j] += __shfl_xor(spart[j], 1, 64);
    spart[j] += __shfl_xor(spart[j], 2, 64);
    spart[j] += __shfl_xor(spart[j], 4, 64);
    spart[j] += __shfl_xor(spart[j], 8, 64);
  }
  if (lrow == 0) {
#pragma unroll
    for (int j = 0; j < 4; ++j) ps_sh[r0 + j][nh] = spart[j];
  }
  __syncthreads();
  if (tid == 0) {
    float sv[CATN];
    float mx = -3.4e38f;
#pragma unroll
    for (int c = 0; c < CATN; ++c) {
      bool mk = (c == CATN - 1) || (mask[b * CATN + c] != 0);
      float s = mk ? (ps_sh[c][0] + ps_sh[c][1]) * ATT_INV : -3.4e38f;
      sv[c] = s;
      mx = fmaxf(mx, s);
    }
    float den = 0.f;
#pragma unroll
    for (int c = 0; c < CATN; ++c) {
      float e = (sv[c] <= -3.3e38f) ? 0.f : expf(sv[c] - mx);
      w_sh[c] = e;
      den += e;
    }
    float inv = 1.0f / den;
#pragma unroll
    for (int c = 0; c < CATN; ++c) w_sh[c] *= inv;
#pragma unroll
    for (int c = CATN; c < 32; ++c) w_sh[c] = 0.f;
  }
  __syncthreads();
  // --- weighted output sum ---
#pragma unroll
  for (int c = 0; c < 13; ++c) {
    int col = (cbeg + c) * 16 + lrow;
    if (col < DD) {
      float bv = afb[col];
      float o = 0.f;
#pragma unroll
      for (int j = 0; j < 4; ++j) {
        float v = fmaxf(acc2[c][j] + bv, 0.f) + bf2f(a_sh[(r0 + j) * 424 + col]);
        o += w_sh[r0 + j] * v;
      }
      o += __shfl_xor(o, 16, 64);
      o += __shfl_xor(o, 32, 64);
      if (lk == 0) osum[rg][col] = o;
    }
  }
  __syncthreads();
  for (int i = tid; i < DD; i += 256)
    out[(size_t)bn * DD + i] = osum[0][i] + osum[1][i];
}

// ============================================================================
extern "C" void kernel_launch(void* const* d_in, const int* in_sizes, int n_in,
                              void* d_out, int out_size, void* d_ws, size_t ws_size,
                              hipStream_t stream) {
  const float* hist  = (const float*)d_in[0];
  const float* cand  = (const float*)d_in[1];
  const float* G     = (const float*)d_in[2];
  const int*   cmask = (const int*)d_in[3];
  const int*   cidx  = (const int*)d_in[4];
  const float* proxy = (const float*)d_in[5];
  const float* gW    = (const float*)d_in[6];
  const float* gb    = (const float*)d_in[7];
  const float* lns   = (const float*)d_in[8];
  const float* lnb   = (const float*)d_in[9];
  const float* Kw    = (const float*)d_in[10];
  const float* Qw    = (const float*)d_in[11];
  const float* Qbb   = (const float*)d_in[12];
  const float* afW   = (const float*)d_in[13];
  const float* afb   = (const float*)d_in[14];
  const float* icKw  = (const float*)d_in[15];
  const float* icQw  = (const float*)d_in[16];
  const float* icQb  = (const float*)d_in[17];
  float* out = (float*)d_out;
  float* ws  = (float*)d_ws;

  // ---- workspace layout (float offsets) ----
  // SLOT0 @0: he (3,020,800) -> later {Pbuf us[64][320][128]=1,310,720 fl ; qbuf ; pbuf}
  // SLOT1 @3,020,800: h1/h2 -> Kbuf [6400][200]
  // SLOT2 @6,041,600: tmpb bf16 [7552][416] -> gf fp32 [6400][400]
  // TB    @9,062,400: [64][416][128] bf16
  // wbase @10,766,336 (1,051,648 us = 525,824 fl) ; bias3 @11,292,160 (608)
  float* he    = ws;
  float* s1    = ws + 3020800;
  float* s2f   = ws + 6041600;
  unsigned short* tmpb = (unsigned short*)(ws + 6041600);
  unsigned short* TB   = (unsigned short*)(ws + 9062400);
  unsigned short* wbase = (unsigned short*)(ws + 10766336);
  float* bias3 = ws + 11292160;
  unsigned short* Pbuf = (unsigned short*)ws;
  float* qbuf  = ws + 1310720;                  // [1024][200]
  float* pbuf  = ws + 1515520;                  // [1024][400]
  float* Kbuf  = s1;
  unsigned short* gW0t  = wbase;
  unsigned short* gW1t  = wbase + 173056;
  unsigned short* afWt  = wbase + 346112;
  unsigned short* Kwt   = wbase + 519168;       // [224][416]
  unsigned short* icKwB = wbase + 612352;       // [416][224]
  unsigned short* icQwB = wbase + 705536;       // [416][224]
  unsigned short* Wqp   = wbase + 798720;       // [608][416]

  // 0. weight prep + fused icQ->p matrix
  k_prep_all<<<3461, 256, 0, stream>>>(gW, afW, Kw, Qw, icQw, icKw, Qbb, icQb, wbase, bias3);
  k_prep_M<<<13, 256, 0, stream>>>(icKwB, icQwB, Wqp);
  // 1. he
  k_concat_he<<<(BN * DD + 255) / 256, 256, 0, stream>>>(hist, proxy, he, BN * DD);
  // 2-4. GCN layer 0
  k_toT<NODES><<<448, 256, 0, stream>>>(he, TB);
  k_gmm<<<256, 256, 0, stream>>>(G, TB, tmpb);
  k_mgb_ln<<<BN / 32, 256, 0, stream>>>(tmpb, gW0t, gb, he, lns, lnb, s1);
  // 5-7. GCN layer 1 (in-place s1)
  k_toT<NODES><<<448, 256, 0, stream>>>(s1, TB);
  k_gmm<<<256, 256, 0, stream>>>(G, TB, tmpb);
  k_mgb_ln<<<BN / 32, 256, 0, stream>>>(tmpb, gW1t, gb + DD, s1, lns + DD, lnb + DD, s1);
  // 8. gf compact -> SLOT2
  k_add_gf<<<(BH * DD + 255) / 256, 256, 0, stream>>>(s1, he, s2f, BH * DD);
  // 9. gfT -> TB
  k_toT<HH><<<448, 256, 0, stream>>>(s2f, TB);
  // 10. K = gf @ Kw -> Kbuf
  k_mg<400, 416, 200, 0><<<BH / 32, 256, 0, stream>>>(s2f, Kwt, nullptr, Kbuf, nullptr);
  // 11. fused Q-proj + p-proj: qbuf / pbuf
  k_mg<400, 416, 608, 6><<<BB * NN / 32, 256, 0, stream>>>(cand, Wqp, bias3, qbuf, pbuf);
  // 12. alpha -> P
  k_palpha<<<BB * NN, 256, 0, stream>>>(Kbuf, qbuf, cidx, Pbuf);
  // 13. fused intra phase -> out
  k_intra<<<BB * NN, 256, 0, stream>>>(Pbuf, TB, afWt, afb, pbuf, cmask, out);
}

// Round 7
// 399.316 us; speedup vs baseline: 1.0407x; 1.0407x over previous
//
#include <hip/hip_runtime.h>
#include <hip/hip_bf16.h>
#include <math.h>

#define BB 64
#define NN 16
#define HH 100
#define DD 400
#define AA 200
#define CATN 19
#define NODES 118            // HH + CATN-1
#define BN (BB*NODES)        // 7552
#define BH (BB*HH)           // 6400
#define ATT_INV 0.07071067811865475f   // 1/sqrt(200)

typedef __attribute__((ext_vector_type(4))) float f32x4;
typedef __attribute__((ext_vector_type(8))) short s16x8;

__device__ __forceinline__ unsigned short f2bf(float f) {
  union { float f; unsigned int u; } v; v.f = f;
  unsigned int r = v.u + 0x7FFFu + ((v.u >> 16) & 1u);
  return (unsigned short)(r >> 16);
}
__device__ __forceinline__ float bf2f(unsigned short u) {
  union { unsigned int i; float f; } v; v.i = ((unsigned int)u) << 16; return v.f;
}

// ---------------------------------------------------------------- concat he
__global__ __launch_bounds__(256) void k_concat_he(const float* __restrict__ hist,
    const float* __restrict__ proxy, float* __restrict__ he, int total) {
  int idx = blockIdx.x * 256 + threadIdx.x;
  if (idx >= total) return;
  int d = idx % DD;
  int bi = idx / DD;
  int i = bi % NODES;
  int b = bi / NODES;
  he[idx] = (i < HH) ? hist[((size_t)b * HH + i) * DD + d] : proxy[(size_t)(i - HH) * DD + d];
}

// ---------------- transpose h[b][RPB][400] fp32 -> T[b][416][128] bf16 (j-padded)
template<int RPB>
__global__ __launch_bounds__(256) void k_toT(const float* __restrict__ h,
    unsigned short* __restrict__ T) {
  __shared__ float t_sh[64][129];
  const int b = blockIdx.x / 7, dt = blockIdx.x % 7;
  const int d0 = dt * 64;
  const int tid = threadIdx.x;
  const int dc = tid & 63, jr = tid >> 6;
  for (int j0 = 0; j0 < 128; j0 += 4) {
    int j = j0 + jr, d = d0 + dc;
    float v = (j < RPB && d < DD) ? h[((size_t)b * RPB + j) * DD + d] : 0.f;
    t_sh[dc][j] = v;
  }
  __syncthreads();
  const int jc = tid & 127, dr2 = tid >> 7;
  for (int di = 0; di < 64; di += 2) {
    int dr = di + dr2;
    int d = d0 + dr;
    if (d < 416) T[((size_t)b * 416 + d) * 128 + jc] = f2bf(t_sh[dr][jc]);
  }
}

// ---------------- graph MFMA: tmpb[b][i][0..415] = bf16( G[b] @ h[b] )
__global__ __launch_bounds__(256) void k_gmm(const float* __restrict__ G,
    const unsigned short* __restrict__ hT, unsigned short* __restrict__ tmpb) {
  __shared__ unsigned short a_sh[32 * 136];
  const int b = blockIdx.x >> 2;
  const int i0 = (blockIdx.x & 3) * 32;
  const int tid = threadIdx.x;
  for (int idx = tid; idx < 32 * 128; idx += 256) {
    int r = idx >> 7, j = idx & 127;
    int i = i0 + r;
    float v = (i < NODES && j < NODES) ? G[((size_t)b * NODES + i) * NODES + j] : 0.f;
    a_sh[r * 136 + j] = f2bf(v);
  }
  __syncthreads();
  const int lane = tid & 63, w = tid >> 6;
  const int lrow = lane & 15, lk = lane >> 4;
  const int rg = w & 1, nh = w >> 1;
  const int cbeg = nh * 13;
  f32x4 acc[13];
#pragma unroll
  for (int c = 0; c < 13; ++c) acc[c] = f32x4{0.f, 0.f, 0.f, 0.f};
  const unsigned short* ap = &a_sh[(rg * 16 + lrow) * 136 + lk * 8];
  const unsigned short* wp = &hT[((size_t)b * 416 + cbeg * 16 + lrow) * 128 + lk * 8];
  for (int ks = 0; ks < 4; ++ks) {
    s16x8 af = *reinterpret_cast<const s16x8*>(ap + ks * 32);
#pragma unroll
    for (int c = 0; c < 13; ++c) {
      s16x8 bf = *reinterpret_cast<const s16x8*>(wp + (size_t)c * 16 * 128 + ks * 32);
      acc[c] = __builtin_amdgcn_mfma_f32_16x16x32_bf16(af, bf, acc[c], 0, 0, 0);
    }
  }
  const int r0 = rg * 16 + lk * 4;
#pragma unroll
  for (int c = 0; c < 13; ++c) {
    int col = (cbeg + c) * 16 + lrow;
#pragma unroll
    for (int j = 0; j < 4; ++j) {
      int i = i0 + r0 + j;
      if (i < NODES)
        tmpb[((size_t)b * NODES + i) * 416 + col] = f2bf(acc[c][j]);
    }
  }
}

// ---------------- dense LN GEMM, bf16 A direct-global: out = LN(relu(A@W+b)+resid)
__global__ __launch_bounds__(256) void k_mgb_ln(
    const unsigned short* __restrict__ A, const unsigned short* __restrict__ Wt,
    const float* __restrict__ bias, const float* __restrict__ resid,
    const float* __restrict__ lns, const float* __restrict__ lnb,
    float* __restrict__ out) {
  __shared__ float ps_sh[32][2][2];
  const int tid = threadIdx.x;
  const size_t row0 = (size_t)blockIdx.x * 32;
  const int lane = tid & 63, w = tid >> 6;
  const int lrow = lane & 15, lk = lane >> 4;
  const int rg = w & 1, nh = w >> 1;
  const int cbeg = nh * 13;
  f32x4 acc[13];
#pragma unroll
  for (int c = 0; c < 13; ++c) acc[c] = f32x4{0.f, 0.f, 0.f, 0.f};
  const unsigned short* ap = &A[(row0 + rg * 16 + lrow) * 416 + lk * 8];
  const unsigned short* wp = &Wt[((size_t)(cbeg * 16) + lrow) * 416 + lk * 8];
  for (int ks = 0; ks < 13; ++ks) {
    s16x8 af = *reinterpret_cast<const s16x8*>(ap + ks * 32);
#pragma unroll
    for (int c = 0; c < 13; ++c) {
      s16x8 bf = *reinterpret_cast<const s16x8*>(wp + (size_t)c * 16 * 416 + ks * 32);
      acc[c] = __builtin_amdgcn_mfma_f32_16x16x32_bf16(af, bf, acc[c], 0, 0, 0);
    }
  }
  const int r0 = rg * 16 + lk * 4;
  float zs[4], zq[4];
#pragma unroll
  for (int j = 0; j < 4; ++j) { zs[j] = 0.f; zq[j] = 0.f; }
#pragma unroll
  for (int c = 0; c < 13; ++c) {
    int col = (cbeg + c) * 16 + lrow;
    bool cv = col < DD;
    float bv = cv ? bias[col] : 0.f;
#pragma unroll
    for (int j = 0; j < 4; ++j) {
      float z = 0.f;
      if (cv)
        z = fmaxf(acc[c][j] + bv, 0.f) + resid[(row0 + r0 + j) * (size_t)DD + col];
      acc[c][j] = z;
      zs[j] += z;
      zq[j] += z * z;
    }
  }
#pragma unroll
  for (int j = 0; j < 4; ++j) {
    zs[j] += __shfl_xor(zs[j], 1, 64); zq[j] += __shfl_xor(zq[j], 1, 64);
    zs[j] += __shfl_xor(zs[j], 2, 64); zq[j] += __shfl_xor(zq[j], 2, 64);
    zs[j] += __shfl_xor(zs[j], 4, 64); zq[j] += __shfl_xor(zq[j], 4, 64);
    zs[j] += __shfl_xor(zs[j], 8, 64); zq[j] += __shfl_xor(zq[j], 8, 64);
  }
  if (lrow == 0) {
#pragma unroll
    for (int j = 0; j < 4; ++j) {
      ps_sh[r0 + j][nh][0] = zs[j];
      ps_sh[r0 + j][nh][1] = zq[j];
    }
  }
  __syncthreads();
  float mu[4], rs[4];
#pragma unroll
  for (int j = 0; j < 4; ++j) {
    float s = ps_sh[r0 + j][0][0] + ps_sh[r0 + j][1][0];
    float q = ps_sh[r0 + j][0][1] + ps_sh[r0 + j][1][1];
    mu[j] = s * (1.0f / DD);
    float var = q * (1.0f / DD) - mu[j] * mu[j];
    rs[j] = 1.0f / sqrtf(var + 1e-5f);
  }
#pragma unroll
  for (int c = 0; c < 13; ++c) {
    int col = (cbeg + c) * 16 + lrow;
    if (col < DD) {
      float sc = lns[col], bo = lnb[col];
#pragma unroll
      for (int j = 0; j < 4; ++j)
        out[(row0 + r0 + j) * (size_t)DD + col] = (acc[c][j] - mu[j]) * rs[j] * sc + bo;
    }
  }
}

// ------------------------------- gf[b*100+i] = h2[b*118+i] + he[b*118+i]  (compact)
__global__ __launch_bounds__(256) void k_add_gf(const float* __restrict__ h2,
    const float* __restrict__ he, float* __restrict__ gf, int total) {
  int idx = blockIdx.x * 256 + threadIdx.x;
  if (idx >= total) return;
  int d = idx % DD;
  int bi = idx / DD;
  int i = bi % HH;
  int b = bi / HH;
  size_t src = ((size_t)b * NODES + i) * DD + d;
  gf[idx] = h2[src] + he[src];
}

// ---------------- one-shot weight prep (bf16 transposed+padded blobs)
// blob map (ushort offsets into wbase):
//   gW0t @0        [416][416]
//   gW1t @173056   [416][416]
//   afW2 @346112   [13][416][32]  ks-major slices for LDS staging
//   Kwt  @519168   [224][416]
//   icKwB@612352   [416][224]
//   icQwB@705536   [416][224]
//   Wqp  @798720   [608][416]  (rows 0..207 = Qw cols; rows 208.. filled by k_prep_M)
// bias3 float[608]: 0..199 Qb ; 208..607 pb[d] = icQb . icKw[d,:]
__global__ __launch_bounds__(256) void k_prep_all(const float* __restrict__ gW,
    const float* __restrict__ afW, const float* __restrict__ Kw,
    const float* __restrict__ Qw, const float* __restrict__ icQw,
    const float* __restrict__ icKw, const float* __restrict__ Qb,
    const float* __restrict__ icQb, unsigned short* __restrict__ wbase,
    float* __restrict__ bias3) {
  int idx = blockIdx.x * 256 + threadIdx.x;
  const int SG = 416 * 416;   // 173056
  const int SK = 224 * 416;   // 93184
  if (idx < SG) {             // gW0t
    int n = idx / 416, k = idx - n * 416;
    wbase[idx] = (n < 400 && k < 400) ? f2bf(gW[(size_t)k * 400 + n]) : (unsigned short)0;
    return;
  }
  idx -= SG;
  if (idx < SG) {             // gW1t
    int n = idx / 416, k = idx - n * 416;
    wbase[173056 + idx] = (n < 400 && k < 400) ? f2bf(gW[160000 + (size_t)k * 400 + n]) : (unsigned short)0;
    return;
  }
  idx -= SG;
  if (idx < SG) {             // afW2 [ks][n][kk], k = ks*32+kk
    int ks = idx / 13312, r = idx - ks * 13312;
    int n = r / 32, kk = r - n * 32;
    int k = ks * 32 + kk;
    wbase[346112 + idx] = (n < 400 && k < 400) ? f2bf(afW[(size_t)k * 400 + n]) : (unsigned short)0;
    return;
  }
  idx -= SG;
  if (idx < SK) {             // Kwt [224 n][416 k]
    int n = idx / 416, k = idx - n * 416;
    wbase[519168 + idx] = (n < 200 && k < 400) ? f2bf(Kw[(size_t)k * 200 + n]) : (unsigned short)0;
    return;
  }
  idx -= SK;
  if (idx < SK) {             // icKwB [416 d][224 a]
    int d = idx / 224, a = idx - d * 224;
    wbase[612352 + idx] = (d < 400 && a < 200) ? f2bf(icKw[(size_t)d * 200 + a]) : (unsigned short)0;
    return;
  }
  idx -= SK;
  if (idx < SK) {             // icQwB [416 k][224 a]
    int k = idx / 224, a = idx - k * 224;
    wbase[705536 + idx] = (k < 400 && a < 200) ? f2bf(icQw[(size_t)k * 200 + a]) : (unsigned short)0;
    return;
  }
  idx -= SK;
  if (idx < 208 * 416) {      // Wqp rows 0..207 (Q part)
    int n = idx / 416, k = idx - n * 416;
    wbase[798720 + idx] = (n < 200 && k < 400) ? f2bf(Qw[(size_t)k * 200 + n]) : (unsigned short)0;
    return;
  }
  idx -= 208 * 416;
  if (idx < 608) {            // bias3
    float v = 0.f;
    if (idx < 200) v = Qb[idx];
    else if (idx >= 208) {
      const float* kr = icKw + (size_t)(idx - 208) * 200;
      float s = 0.f;
      for (int a = 0; a < 200; ++a) s += icQb[a] * kr[a];
      v = s;
    }
    bias3[idx] = v;
  }
}

// ---------------- M-prep: Wqp[208+d][k] = bf16( sum_a icKw[d,a]*icQw[k,a] ), MFMA
__global__ __launch_bounds__(256) void k_prep_M(const unsigned short* __restrict__ icKwB,
    const unsigned short* __restrict__ icQwB, unsigned short* __restrict__ wqp) {
  const int tid = threadIdx.x;
  const size_t row0 = (size_t)blockIdx.x * 32;
  const int lane = tid & 63, w = tid >> 6;
  const int lrow = lane & 15, lk = lane >> 4;
  const int rg = w & 1, nh = w >> 1;
  const int cbeg = nh * 13;
  f32x4 acc[13];
#pragma unroll
  for (int c = 0; c < 13; ++c) acc[c] = f32x4{0.f, 0.f, 0.f, 0.f};
  const unsigned short* ap = &icKwB[(row0 + rg * 16 + lrow) * 224 + lk * 8];
  const unsigned short* bp = &icQwB[((size_t)(cbeg * 16) + lrow) * 224 + lk * 8];
  for (int ks = 0; ks < 7; ++ks) {
    s16x8 af = *reinterpret_cast<const s16x8*>(ap + ks * 32);
#pragma unroll
    for (int c = 0; c < 13; ++c) {
      s16x8 bf = *reinterpret_cast<const s16x8*>(bp + (size_t)c * 16 * 224 + ks * 32);
      acc[c] = __builtin_amdgcn_mfma_f32_16x16x32_bf16(af, bf, acc[c], 0, 0, 0);
    }
  }
  const int r0 = rg * 16 + lk * 4;
#pragma unroll
  for (int c = 0; c < 13; ++c) {
    int k = (cbeg + c) * 16 + lrow;
#pragma unroll
    for (int j = 0; j < 4; ++j) {
      size_t d = row0 + r0 + j;
      if (d < 400) wqp[(208 + d) * 416 + k] = f2bf(acc[c][j]);
    }
  }
}

// =================== fp32-A MFMA GEMM. EPI: 0 plain(colguard), 6 QP dual-output
template<int KDIM, int KPAD, int NOUT, int EPI>
__global__ __launch_bounds__(256) void k_mg(
    const float* __restrict__ A, const unsigned short* __restrict__ Wt,
    const float* __restrict__ bias, float* __restrict__ out, float* __restrict__ out2) {
  constexpr int APITCH = KPAD + 8;
  constexpr int NF = (NOUT + 15) / 16;
  constexpr int NF0 = (NF + 1) / 2;
  constexpr int KS = KPAD / 32;
  constexpr int E4 = KDIM / 4;
  constexpr int PADN = KPAD - KDIM;
  __shared__ unsigned short a_sh[32 * APITCH];
  const int tid = threadIdx.x;
  const size_t row0 = (size_t)blockIdx.x * 32;
  for (int i = tid; i < 32 * E4; i += 256) {
    int r = i / E4, c4 = i - r * E4;
    const float4 v = *reinterpret_cast<const float4*>(&A[(row0 + r) * (size_t)KDIM + c4 * 4]);
    unsigned int lo = (unsigned int)f2bf(v.x) | ((unsigned int)f2bf(v.y) << 16);
    unsigned int hi = (unsigned int)f2bf(v.z) | ((unsigned int)f2bf(v.w) << 16);
    *reinterpret_cast<uint2*>(&a_sh[r * APITCH + c4 * 4]) = make_uint2(lo, hi);
  }
  for (int i = tid; i < 32 * PADN; i += 256) {
    int r = i / PADN, c = i - r * PADN;
    a_sh[r * APITCH + KDIM + c] = 0;
  }
  __syncthreads();
  const int lane = tid & 63, w = tid >> 6;
  const int lrow = lane & 15, lk = lane >> 4;
  const int rg = w & 1, nh = w >> 1;
  const int cbeg = nh * NF0;
  f32x4 acc[NF0];
#pragma unroll
  for (int c = 0; c < NF0; ++c) acc[c] = f32x4{0.f, 0.f, 0.f, 0.f};
  const unsigned short* ap = &a_sh[(rg * 16 + lrow) * APITCH + lk * 8];
  const unsigned short* wp = &Wt[((size_t)(cbeg * 16) + lrow) * KPAD + lk * 8];
  for (int ks = 0; ks < KS; ++ks) {
    s16x8 af = *reinterpret_cast<const s16x8*>(ap + ks * 32);
#pragma unroll
    for (int c = 0; c < NF0; ++c) {
      s16x8 bf = *reinterpret_cast<const s16x8*>(wp + (size_t)c * 16 * KPAD + ks * 32);
      acc[c] = __builtin_amdgcn_mfma_f32_16x16x32_bf16(af, bf, acc[c], 0, 0, 0);
    }
  }
  const int r0 = rg * 16 + lk * 4;
  if (EPI == 0) {
#pragma unroll
    for (int c = 0; c < NF0; ++c) {
      int col = (cbeg + c) * 16 + lrow;
      if (col < NOUT) {
#pragma unroll
        for (int j = 0; j < 4; ++j)
          out[(row0 + r0 + j) * (size_t)NOUT + col] = acc[c][j];
      }
    }
  } else {  // EPI == 6: col<200 -> out[.,col]+b ; 208<=col<608 -> out2[.,col-208]+b
#pragma unroll
    for (int c = 0; c < NF0; ++c) {
      int col = (cbeg + c) * 16 + lrow;
      if (col < 200) {
        float bv = bias[col];
#pragma unroll
        for (int j = 0; j < 4; ++j)
          out[(row0 + r0 + j) * (size_t)AA + col] = acc[c][j] + bv;
      } else if (col >= 208 && col < 608) {
        float bv = bias[col];
#pragma unroll
        for (int j = 0; j < 4; ++j)
          out2[(row0 + r0 + j) * (size_t)DD + (col - 208)] = acc[c][j] + bv;
      }
    }
  }
}

// --------- alpha segment-softmax -> P bf16 [b][320 pitch][128]  (XCD-swizzled)
__global__ __launch_bounds__(256) void k_palpha(const float* __restrict__ K,
    const float* __restrict__ Q, const int* __restrict__ cat,
    unsigned short* __restrict__ P) {
  __shared__ float q_sh[AA];
  __shared__ float a_sh[HH];
  __shared__ int c_sh[HH];
  __shared__ float smax[CATN], sden[CATN];
  // XCD-aware swizzle: all 16 n of a given b on the same XCD (b-local L2)
  const int i = blockIdx.x;
  const int b = ((i >> 7) << 3) | (i & 7);
  const int n = (i >> 3) & 15;
  const int bn = b * 16 + n;
  const int tid = threadIdx.x;
  if (tid < AA) q_sh[tid] = Q[(size_t)bn * AA + tid];
  if (tid < HH) c_sh[tid] = cat[b * HH + tid];
  __syncthreads();
  if (tid < 2 * HH) {
    int h = tid >> 1, half = tid & 1;
    const float* kp = K + ((size_t)b * HH + h) * AA + half * 100;
    const float* qp = q_sh + half * 100;
    float s = 0.f;
#pragma unroll 4
    for (int a = 0; a < 100; ++a) s += kp[a] * qp[a];
    s += __shfl_xor(s, 1, 64);
    if (half == 0) a_sh[h] = s * ATT_INV;
  }
  __syncthreads();
  if (tid < CATN) {
    float m = -3.4e38f;
    for (int h = 0; h < HH; ++h)
      if (c_sh[h] == tid) m = fmaxf(m, a_sh[h]);
    smax[tid] = m;
  }
  __syncthreads();
  if (tid < HH) a_sh[tid] = expf(a_sh[tid] - smax[c_sh[tid]]);
  __syncthreads();
  if (tid < CATN) {
    float dsum = 0.f;
    for (int h = 0; h < HH; ++h)
      if (c_sh[h] == tid) dsum += a_sh[h];
    sden[tid] = dsum;
  }
  __syncthreads();
  if (tid < HH) a_sh[tid] = a_sh[tid] / sden[c_sh[tid]];
  __syncthreads();
  for (int idx = tid; idx < CATN * 128; idx += 256) {
    int c = idx >> 7, h = idx & 127;
    float v = (h < HH && c_sh[h] == c) ? a_sh[h] : 0.f;
    P[((size_t)b * 320 + n * CATN + c) * 128 + h] = f2bf(v);
  }
}

// --------- fused intra phase (XCD-swizzled, LDS-staged GEMM2 B)
// GEMM1 intra = P@gfT (M=32,K=128) -> LDS bf16 (rows >= CATN zeroed) ->
// GEMM2 affine with B slices [416][32] staged through LDS (prefetch 1 ahead) ->
// v = relu(+afb)+resid ; s = v.p ; masked softmax(19) ; out = sum_c w*v
__global__ __launch_bounds__(256) void k_intra(
    const unsigned short* __restrict__ P, const unsigned short* __restrict__ gfT,
    const unsigned short* __restrict__ afW2, const float* __restrict__ afb,
    const float* __restrict__ pbuf, const int* __restrict__ mask,
    float* __restrict__ out) {
  __shared__ unsigned short a_sh[32 * 424];    // 26.5 KB
  __shared__ unsigned short Bs[416 * 32];      // 26.0 KB  (one K-slice of afW)
  __shared__ float p_sh[DD];
  __shared__ float ps_sh[32][2];
  __shared__ float w_sh[32];
  __shared__ float osum[2][DD];
  // XCD-aware swizzle (same as k_palpha): b-locality for gfT/P reads
  const int ii = blockIdx.x;
  const int b = ((ii >> 7) << 3) | (ii & 7);
  const int n = (ii >> 3) & 15;
  const int bn = b * 16 + n;
  const int tid = threadIdx.x;
  for (int i = tid; i < DD; i += 256) p_sh[i] = pbuf[(size_t)bn * DD + i];
  const int lane = tid & 63, w = tid >> 6;
  const int lrow = lane & 15, lk = lane >> 4;
  const int rg = w & 1, nh = w >> 1;
  const int cbeg = nh * 13;
  const int r0 = rg * 16 + lk * 4;
  // --- GEMM1 ---
  f32x4 acc[13];
#pragma unroll
  for (int c = 0; c < 13; ++c) acc[c] = f32x4{0.f, 0.f, 0.f, 0.f};
  {
    const unsigned short* ap = &P[((size_t)b * 320 + n * CATN + rg * 16 + lrow) * 128 + lk * 8];
    const unsigned short* bp = &gfT[((size_t)b * 416 + cbeg * 16 + lrow) * 128 + lk * 8];
    for (int ks = 0; ks < 4; ++ks) {
      s16x8 af = *reinterpret_cast<const s16x8*>(ap + ks * 32);
#pragma unroll
      for (int c = 0; c < 13; ++c) {
        s16x8 bf = *reinterpret_cast<const s16x8*>(bp + (size_t)c * 16 * 128 + ks * 32);
        acc[c] = __builtin_amdgcn_mfma_f32_16x16x32_bf16(af, bf, acc[c], 0, 0, 0);
      }
    }
  }
  // stage intra tile (bf16) -> a_sh; rows >= CATN zeroed (NaN guard, n==15 case)
#pragma unroll
  for (int c = 0; c < 13; ++c) {
    int col = (cbeg + c) * 16 + lrow;
#pragma unroll
    for (int j = 0; j < 4; ++j)
      a_sh[(r0 + j) * 424 + col] = f2bf((r0 + j) < CATN ? acc[c][j] : 0.f);
  }
  // --- GEMM2: B slices streamed global->reg->LDS, prefetch 1 slice ahead ---
  f32x4 acc2[13];
#pragma unroll
  for (int c = 0; c < 13; ++c) acc2[c] = f32x4{0.f, 0.f, 0.f, 0.f};
  uint4 breg[7];
  {
    const uint4* g0 = reinterpret_cast<const uint4*>(afW2);   // slice 0
#pragma unroll
    for (int it = 0; it < 6; ++it) breg[it] = g0[it * 256 + tid];
    if (tid < 128) breg[6] = g0[6 * 256 + tid];
  }
  const unsigned short* ap2 = &a_sh[(rg * 16 + lrow) * 424 + lk * 8];
  const unsigned short* bp2 = &Bs[(cbeg * 16 + lrow) * 32 + lk * 8];
  for (int ks = 0; ks < 13; ++ks) {
    __syncthreads();   // prev-slice MFMA reads done (and a_sh writes at ks==0)
#pragma unroll
    for (int it = 0; it < 6; ++it)
      *reinterpret_cast<uint4*>(&Bs[it * 2048 + tid * 8]) = breg[it];
    if (tid < 128)
      *reinterpret_cast<uint4*>(&Bs[6 * 2048 + tid * 8]) = breg[6];
    if (ks < 12) {
      const uint4* gn = reinterpret_cast<const uint4*>(afW2 + (ks + 1) * 13312);
#pragma unroll
      for (int it = 0; it < 6; ++it) breg[it] = gn[it * 256 + tid];
      if (tid < 128) breg[6] = gn[6 * 256 + tid];
    }
    __syncthreads();   // Bs ready
    s16x8 af = *reinterpret_cast<const s16x8*>(ap2 + ks * 32);
#pragma unroll
    for (int c = 0; c < 13; ++c) {
      s16x8 bf = *reinterpret_cast<const s16x8*>(bp2 + c * 16 * 32);
      acc2[c] = __builtin_amdgcn_mfma_f32_16x16x32_bf16(af, bf, acc2[c], 0, 0, 0);
    }
  }
  // --- s-dot ---
  float spart[4] = {0.f, 0.f, 0.f, 0.f};
#pragma unroll
  for (int c = 0; c < 13; ++c) {
    int col = (cbeg + c) * 16 + lrow;
    if (col < DD) {
      float bv = afb[col], pv = p_sh[col];
#pragma unroll
      for (int j = 0; j < 4; ++j) {
        float v = fmaxf(acc2[c][j] + bv, 0.f) + bf2f(a_sh[(r0 + j) * 424 + col]);
        spart[j] += v * pv;
      }
    }
  }
#pragma unroll
  for (int j = 0; j < 4; ++j) {
    spart[j] += __shfl_xor(spart[j], 1, 64);
    spart[j] += __shfl_xor(spart[j], 2, 64);
    spart[j] += __shfl_xor(spart[j], 4, 64);
    spart[j] += __shfl_xor(spart[j], 8, 64);
  }
  if (lrow == 0) {
#pragma unroll
    for (int j = 0; j < 4; ++j) ps_sh[r0 + j][nh] = spart[j];
  }
  __syncthreads();
  if (tid == 0) {
    float sv[CATN];
    float mx = -3.4e38f;
#pragma unroll
    for (int c = 0; c < CATN; ++c) {
      bool mk = (c == CATN - 1) || (mask[b * CATN + c] != 0);
      float s = mk ? (ps_sh[c][0] + ps_sh[c][1]) * ATT_INV : -3.4e38f;
      sv[c] = s;
      mx = fmaxf(mx, s);
    }
    float den = 0.f;
#pragma unroll
    for (int c = 0; c < CATN; ++c) {
      float e = (sv[c] <= -3.3e38f) ? 0.f : expf(sv[c] - mx);
      w_sh[c] = e;
      den += e;
    }
    float inv = 1.0f / den;
#pragma unroll
    for (int c = 0; c < CATN; ++c) w_sh[c] *= inv;
#pragma unroll
    for (int c = CATN; c < 32; ++c) w_sh[c] = 0.f;
  }
  __syncthreads();
  // --- weighted output sum ---
#pragma unroll
  for (int c = 0; c < 13; ++c) {
    int col = (cbeg + c) * 16 + lrow;
    if (col < DD) {
      float bv = afb[col];
      float o = 0.f;
#pragma unroll
      for (int j = 0; j < 4; ++j) {
        float v = fmaxf(acc2[c][j] + bv, 0.f) + bf2f(a_sh[(r0 + j) * 424 + col]);
        o += w_sh[r0 + j] * v;
      }
      o += __shfl_xor(o, 16, 64);
      o += __shfl_xor(o, 32, 64);
      if (lk == 0) osum[rg][col] = o;
    }
  }
  __syncthreads();
  for (int i = tid; i < DD; i += 256)
    out[(size_t)bn * DD + i] = osum[0][i] + osum[1][i];
}

// ============================================================================
extern "C" void kernel_launch(void* const* d_in, const int* in_sizes, int n_in,
                              void* d_out, int out_size, void* d_ws, size_t ws_size,
                              hipStream_t stream) {
  const float* hist  = (const float*)d_in[0];
  const float* cand  = (const float*)d_in[1];
  const float* G     = (const float*)d_in[2];
  const int*   cmask = (const int*)d_in[3];
  const int*   cidx  = (const int*)d_in[4];
  const float* proxy = (const float*)d_in[5];
  const float* gW    = (const float*)d_in[6];
  const float* gb    = (const float*)d_in[7];
  const float* lns   = (const float*)d_in[8];
  const float* lnb   = (const float*)d_in[9];
  const float* Kw    = (const float*)d_in[10];
  const float* Qw    = (const float*)d_in[11];
  const float* Qbb   = (const float*)d_in[12];
  const float* afW   = (const float*)d_in[13];
  const float* afb   = (const float*)d_in[14];
  const float* icKw  = (const float*)d_in[15];
  const float* icQw  = (const float*)d_in[16];
  const float* icQb  = (const float*)d_in[17];
  float* out = (float*)d_out;
  float* ws  = (float*)d_ws;

  // ---- workspace layout (float offsets) ----
  // SLOT0 @0: he (3,020,800) -> later {Pbuf us[64][320][128]=1,310,720 fl ; qbuf ; pbuf}
  // SLOT1 @3,020,800: h1/h2 -> Kbuf [6400][200]
  // SLOT2 @6,041,600: tmpb bf16 [7552][416] -> gf fp32 [6400][400]
  // TB    @9,062,400: [64][416][128] bf16
  // wbase @10,766,336 (1,051,648 us = 525,824 fl) ; bias3 @11,292,160 (608)
  float* he    = ws;
  float* s1    = ws + 3020800;
  float* s2f   = ws + 6041600;
  unsigned short* tmpb = (unsigned short*)(ws + 6041600);
  unsigned short* TB   = (unsigned short*)(ws + 9062400);
  unsigned short* wbase = (unsigned short*)(ws + 10766336);
  float* bias3 = ws + 11292160;
  unsigned short* Pbuf = (unsigned short*)ws;
  float* qbuf  = ws + 1310720;                  // [1024][200]
  float* pbuf  = ws + 1515520;                  // [1024][400]
  float* Kbuf  = s1;
  unsigned short* gW0t  = wbase;
  unsigned short* gW1t  = wbase + 173056;
  unsigned short* afW2  = wbase + 346112;       // [13][416][32]
  unsigned short* Kwt   = wbase + 519168;       // [224][416]
  unsigned short* icKwB = wbase + 612352;       // [416][224]
  unsigned short* icQwB = wbase + 705536;       // [416][224]
  unsigned short* Wqp   = wbase + 798720;       // [608][416]

  // 0. weight prep + fused icQ->p matrix
  k_prep_all<<<3461, 256, 0, stream>>>(gW, afW, Kw, Qw, icQw, icKw, Qbb, icQb, wbase, bias3);
  k_prep_M<<<13, 256, 0, stream>>>(icKwB, icQwB, Wqp);
  // 1. he
  k_concat_he<<<(BN * DD + 255) / 256, 256, 0, stream>>>(hist, proxy, he, BN * DD);
  // 2-4. GCN layer 0
  k_toT<NODES><<<448, 256, 0, stream>>>(he, TB);
  k_gmm<<<256, 256, 0, stream>>>(G, TB, tmpb);
  k_mgb_ln<<<BN / 32, 256, 0, stream>>>(tmpb, gW0t, gb, he, lns, lnb, s1);
  // 5-7. GCN layer 1 (in-place s1)
  k_toT<NODES><<<448, 256, 0, stream>>>(s1, TB);
  k_gmm<<<256, 256, 0, stream>>>(G, TB, tmpb);
  k_mgb_ln<<<BN / 32, 256, 0, stream>>>(tmpb, gW1t, gb + DD, s1, lns + DD, lnb + DD, s1);
  // 8. gf compact -> SLOT2
  k_add_gf<<<(BH * DD + 255) / 256, 256, 0, stream>>>(s1, he, s2f, BH * DD);
  // 9. gfT -> TB
  k_toT<HH><<<448, 256, 0, stream>>>(s2f, TB);
  // 10. K = gf @ Kw -> Kbuf
  k_mg<400, 416, 200, 0><<<BH / 32, 256, 0, stream>>>(s2f, Kwt, nullptr, Kbuf, nullptr);
  // 11. fused Q-proj + p-proj: qbuf / pbuf
  k_mg<400, 416, 608, 6><<<BB * NN / 32, 256, 0, stream>>>(cand, Wqp, bias3, qbuf, pbuf);
  // 12. alpha -> P (XCD-swizzled)
  k_palpha<<<BB * NN, 256, 0, stream>>>(Kbuf, qbuf, cidx, Pbuf);
  // 13. fused intra phase -> out (XCD-swizzled, LDS-staged B)
  k_intra<<<BB * NN, 256, 0, stream>>>(Pbuf, TB, afW2, afb, pbuf, cmask, out);
}

// Round 8
// 373.491 us; speedup vs baseline: 1.1127x; 1.0691x over previous
//
#include <hip/hip_runtime.h>
#include <hip/hip_bf16.h>
#include <math.h>

#define BB 64
#define NN 16
#define HH 100
#define DD 400
#define AA 200
#define CATN 19
#define NODES 118            // HH + CATN-1
#define BN (BB*NODES)        // 7552
#define BH (BB*HH)           // 6400
#define ATT_INV 0.07071067811865475f   // 1/sqrt(200)

typedef __attribute__((ext_vector_type(4))) float f32x4;
typedef __attribute__((ext_vector_type(8))) short s16x8;

__device__ __forceinline__ unsigned short f2bf(float f) {
  union { float f; unsigned int u; } v; v.f = f;
  unsigned int r = v.u + 0x7FFFu + ((v.u >> 16) & 1u);
  return (unsigned short)(r >> 16);
}

// ---------------------------------------------------------------- concat he
__global__ __launch_bounds__(256) void k_concat_he(const float* __restrict__ hist,
    const float* __restrict__ proxy, float* __restrict__ he, int total) {
  int idx = blockIdx.x * 256 + threadIdx.x;
  if (idx >= total) return;
  int d = idx % DD;
  int bi = idx / DD;
  int i = bi % NODES;
  int b = bi / NODES;
  he[idx] = (i < HH) ? hist[((size_t)b * HH + i) * DD + d] : proxy[(size_t)(i - HH) * DD + d];
}

// ---------------- transpose h[b][RPB][400] fp32 -> T[b][416][128] bf16 (j-padded)
template<int RPB>
__global__ __launch_bounds__(256) void k_toT(const float* __restrict__ h,
    unsigned short* __restrict__ T) {
  __shared__ float t_sh[64][129];
  const int b = blockIdx.x / 7, dt = blockIdx.x % 7;
  const int d0 = dt * 64;
  const int tid = threadIdx.x;
  const int dc = tid & 63, jr = tid >> 6;
  for (int j0 = 0; j0 < 128; j0 += 4) {
    int j = j0 + jr, d = d0 + dc;
    float v = (j < RPB && d < DD) ? h[((size_t)b * RPB + j) * DD + d] : 0.f;
    t_sh[dc][j] = v;
  }
  __syncthreads();
  const int jc = tid & 127, dr2 = tid >> 7;
  for (int di = 0; di < 64; di += 2) {
    int dr = di + dr2;
    int d = d0 + dr;
    if (d < 416) T[((size_t)b * 416 + d) * 128 + jc] = f2bf(t_sh[dr][jc]);
  }
}

// ---------------- graph MFMA: tmpb[b][i][0..415] = bf16( G[b] @ h[b] )
__global__ __launch_bounds__(256) void k_gmm(const float* __restrict__ G,
    const unsigned short* __restrict__ hT, unsigned short* __restrict__ tmpb) {
  __shared__ unsigned short a_sh[32 * 136];
  const int b = blockIdx.x >> 2;
  const int i0 = (blockIdx.x & 3) * 32;
  const int tid = threadIdx.x;
  for (int idx = tid; idx < 32 * 128; idx += 256) {
    int r = idx >> 7, j = idx & 127;
    int i = i0 + r;
    float v = (i < NODES && j < NODES) ? G[((size_t)b * NODES + i) * NODES + j] : 0.f;
    a_sh[r * 136 + j] = f2bf(v);
  }
  __syncthreads();
  const int lane = tid & 63, w = tid >> 6;
  const int lrow = lane & 15, lk = lane >> 4;
  const int rg = w & 1, nh = w >> 1;
  const int cbeg = nh * 13;
  f32x4 acc[13];
#pragma unroll
  for (int c = 0; c < 13; ++c) acc[c] = f32x4{0.f, 0.f, 0.f, 0.f};
  const unsigned short* ap = &a_sh[(rg * 16 + lrow) * 136 + lk * 8];
  const unsigned short* wp = &hT[((size_t)b * 416 + cbeg * 16 + lrow) * 128 + lk * 8];
  for (int ks = 0; ks < 4; ++ks) {
    s16x8 af = *reinterpret_cast<const s16x8*>(ap + ks * 32);
#pragma unroll
    for (int c = 0; c < 13; ++c) {
      s16x8 bf = *reinterpret_cast<const s16x8*>(wp + (size_t)c * 16 * 128 + ks * 32);
      acc[c] = __builtin_amdgcn_mfma_f32_16x16x32_bf16(af, bf, acc[c], 0, 0, 0);
    }
  }
  const int r0 = rg * 16 + lk * 4;
#pragma unroll
  for (int c = 0; c < 13; ++c) {
    int col = (cbeg + c) * 16 + lrow;
#pragma unroll
    for (int j = 0; j < 4; ++j) {
      int i = i0 + r0 + j;
      if (i < NODES)
        tmpb[((size_t)b * NODES + i) * 416 + col] = f2bf(acc[c][j]);
    }
  }
}

// ---------------- dense LN GEMM, bf16 A direct-global: out = LN(relu(A@W+b)+resid)
__global__ __launch_bounds__(256) void k_mgb_ln(
    const unsigned short* __restrict__ A, const unsigned short* __restrict__ Wt,
    const float* __restrict__ bias, const float* __restrict__ resid,
    const float* __restrict__ lns, const float* __restrict__ lnb,
    float* __restrict__ out) {
  __shared__ float ps_sh[32][2][2];
  const int tid = threadIdx.x;
  const size_t row0 = (size_t)blockIdx.x * 32;
  const int lane = tid & 63, w = tid >> 6;
  const int lrow = lane & 15, lk = lane >> 4;
  const int rg = w & 1, nh = w >> 1;
  const int cbeg = nh * 13;
  f32x4 acc[13];
#pragma unroll
  for (int c = 0; c < 13; ++c) acc[c] = f32x4{0.f, 0.f, 0.f, 0.f};
  const unsigned short* ap = &A[(row0 + rg * 16 + lrow) * 416 + lk * 8];
  const unsigned short* wp = &Wt[((size_t)(cbeg * 16) + lrow) * 416 + lk * 8];
  for (int ks = 0; ks < 13; ++ks) {
    s16x8 af = *reinterpret_cast<const s16x8*>(ap + ks * 32);
#pragma unroll
    for (int c = 0; c < 13; ++c) {
      s16x8 bf = *reinterpret_cast<const s16x8*>(wp + (size_t)c * 16 * 416 + ks * 32);
      acc[c] = __builtin_amdgcn_mfma_f32_16x16x32_bf16(af, bf, acc[c], 0, 0, 0);
    }
  }
  const int r0 = rg * 16 + lk * 4;
  float zs[4], zq[4];
#pragma unroll
  for (int j = 0; j < 4; ++j) { zs[j] = 0.f; zq[j] = 0.f; }
#pragma unroll
  for (int c = 0; c < 13; ++c) {
    int col = (cbeg + c) * 16 + lrow;
    bool cv = col < DD;
    float bv = cv ? bias[col] : 0.f;
#pragma unroll
    for (int j = 0; j < 4; ++j) {
      float z = 0.f;
      if (cv)
        z = fmaxf(acc[c][j] + bv, 0.f) + resid[(row0 + r0 + j) * (size_t)DD + col];
      acc[c][j] = z;
      zs[j] += z;
      zq[j] += z * z;
    }
  }
#pragma unroll
  for (int j = 0; j < 4; ++j) {
    zs[j] += __shfl_xor(zs[j], 1, 64); zq[j] += __shfl_xor(zq[j], 1, 64);
    zs[j] += __shfl_xor(zs[j], 2, 64); zq[j] += __shfl_xor(zq[j], 2, 64);
    zs[j] += __shfl_xor(zs[j], 4, 64); zq[j] += __shfl_xor(zq[j], 4, 64);
    zs[j] += __shfl_xor(zs[j], 8, 64); zq[j] += __shfl_xor(zq[j], 8, 64);
  }
  if (lrow == 0) {
#pragma unroll
    for (int j = 0; j < 4; ++j) {
      ps_sh[r0 + j][nh][0] = zs[j];
      ps_sh[r0 + j][nh][1] = zq[j];
    }
  }
  __syncthreads();
  float mu[4], rs[4];
#pragma unroll
  for (int j = 0; j < 4; ++j) {
    float s = ps_sh[r0 + j][0][0] + ps_sh[r0 + j][1][0];
    float q = ps_sh[r0 + j][0][1] + ps_sh[r0 + j][1][1];
    mu[j] = s * (1.0f / DD);
    float var = q * (1.0f / DD) - mu[j] * mu[j];
    rs[j] = 1.0f / sqrtf(var + 1e-5f);
  }
#pragma unroll
  for (int c = 0; c < 13; ++c) {
    int col = (cbeg + c) * 16 + lrow;
    if (col < DD) {
      float sc = lns[col], bo = lnb[col];
#pragma unroll
      for (int j = 0; j < 4; ++j)
        out[(row0 + r0 + j) * (size_t)DD + col] = (acc[c][j] - mu[j]) * rs[j] * sc + bo;
    }
  }
}

// ------------------------------- gf[b*100+i] = h2[b*118+i] + he[b*118+i]  (compact)
__global__ __launch_bounds__(256) void k_add_gf(const float* __restrict__ h2,
    const float* __restrict__ he, float* __restrict__ gf, int total) {
  int idx = blockIdx.x * 256 + threadIdx.x;
  if (idx >= total) return;
  int d = idx % DD;
  int bi = idx / DD;
  int i = bi % HH;
  int b = bi / HH;
  size_t src = ((size_t)b * NODES + i) * DD + d;
  gf[idx] = h2[src] + he[src];
}

// ---------------- one-shot weight prep (bf16 transposed+padded blobs)
// blob map (ushort offsets into wbase):
//   gW0t @0        [416][416]
//   gW1t @173056   [416][416]
//   afWt @346112   [416][416]
//   Kwt  @519168   [224][416]
//   icKwB@612352   [416][224]
//   icQwB@705536   [416][224]
//   Wqp  @798720   [608][416]  (rows 0..207 = Qw cols; rows 208.. by k_prep_M)
// bias3 float[608]: 0..199 Qb ; 208..607 pb[d] = icQb . icKw[d,:]
__global__ __launch_bounds__(256) void k_prep_all(const float* __restrict__ gW,
    const float* __restrict__ afW, const float* __restrict__ Kw,
    const float* __restrict__ Qw, const float* __restrict__ icQw,
    const float* __restrict__ icKw, const float* __restrict__ Qb,
    const float* __restrict__ icQb, unsigned short* __restrict__ wbase,
    float* __restrict__ bias3) {
  int idx = blockIdx.x * 256 + threadIdx.x;
  const int SG = 416 * 416;   // 173056
  const int SK = 224 * 416;   // 93184
  if (idx < SG) {             // gW0t
    int n = idx / 416, k = idx - n * 416;
    wbase[idx] = (n < 400 && k < 400) ? f2bf(gW[(size_t)k * 400 + n]) : (unsigned short)0;
    return;
  }
  idx -= SG;
  if (idx < SG) {             // gW1t
    int n = idx / 416, k = idx - n * 416;
    wbase[173056 + idx] = (n < 400 && k < 400) ? f2bf(gW[160000 + (size_t)k * 400 + n]) : (unsigned short)0;
    return;
  }
  idx -= SG;
  if (idx < SG) {             // afWt
    int n = idx / 416, k = idx - n * 416;
    wbase[346112 + idx] = (n < 400 && k < 400) ? f2bf(afW[(size_t)k * 400 + n]) : (unsigned short)0;
    return;
  }
  idx -= SG;
  if (idx < SK) {             // Kwt [224 n][416 k]
    int n = idx / 416, k = idx - n * 416;
    wbase[519168 + idx] = (n < 200 && k < 400) ? f2bf(Kw[(size_t)k * 200 + n]) : (unsigned short)0;
    return;
  }
  idx -= SK;
  if (idx < SK) {             // icKwB [416 d][224 a]
    int d = idx / 224, a = idx - d * 224;
    wbase[612352 + idx] = (d < 400 && a < 200) ? f2bf(icKw[(size_t)d * 200 + a]) : (unsigned short)0;
    return;
  }
  idx -= SK;
  if (idx < SK) {             // icQwB [416 k][224 a]
    int k = idx / 224, a = idx - k * 224;
    wbase[705536 + idx] = (k < 400 && a < 200) ? f2bf(icQw[(size_t)k * 200 + a]) : (unsigned short)0;
    return;
  }
  idx -= SK;
  if (idx < 208 * 416) {      // Wqp rows 0..207 (Q part)
    int n = idx / 416, k = idx - n * 416;
    wbase[798720 + idx] = (n < 200 && k < 400) ? f2bf(Qw[(size_t)k * 200 + n]) : (unsigned short)0;
    return;
  }
  idx -= 208 * 416;
  if (idx < 608) {            // bias3
    float v = 0.f;
    if (idx < 200) v = Qb[idx];
    else if (idx >= 208) {
      const float* kr = icKw + (size_t)(idx - 208) * 200;
      float s = 0.f;
      for (int a = 0; a < 200; ++a) s += icQb[a] * kr[a];
      v = s;
    }
    bias3[idx] = v;
  }
}

// ---------------- M-prep: Wqp[208+d][k] = bf16( sum_a icKw[d,a]*icQw[k,a] ), MFMA
__global__ __launch_bounds__(256) void k_prep_M(const unsigned short* __restrict__ icKwB,
    const unsigned short* __restrict__ icQwB, unsigned short* __restrict__ wqp) {
  const int tid = threadIdx.x;
  const size_t row0 = (size_t)blockIdx.x * 32;
  const int lane = tid & 63, w = tid >> 6;
  const int lrow = lane & 15, lk = lane >> 4;
  const int rg = w & 1, nh = w >> 1;
  const int cbeg = nh * 13;
  f32x4 acc[13];
#pragma unroll
  for (int c = 0; c < 13; ++c) acc[c] = f32x4{0.f, 0.f, 0.f, 0.f};
  const unsigned short* ap = &icKwB[(row0 + rg * 16 + lrow) * 224 + lk * 8];
  const unsigned short* bp = &icQwB[((size_t)(cbeg * 16) + lrow) * 224 + lk * 8];
  for (int ks = 0; ks < 7; ++ks) {
    s16x8 af = *reinterpret_cast<const s16x8*>(ap + ks * 32);
#pragma unroll
    for (int c = 0; c < 13; ++c) {
      s16x8 bf = *reinterpret_cast<const s16x8*>(bp + (size_t)c * 16 * 224 + ks * 32);
      acc[c] = __builtin_amdgcn_mfma_f32_16x16x32_bf16(af, bf, acc[c], 0, 0, 0);
    }
  }
  const int r0 = rg * 16 + lk * 4;
#pragma unroll
  for (int c = 0; c < 13; ++c) {
    int k = (cbeg + c) * 16 + lrow;
#pragma unroll
    for (int j = 0; j < 4; ++j) {
      size_t d = row0 + r0 + j;
      if (d < 400) wqp[(208 + d) * 416 + k] = f2bf(acc[c][j]);
    }
  }
}

// =================== fp32-A MFMA GEMM, v2 decomposition:
// 4 waves = 4 N-quarters; each wave computes BOTH 16-row groups (each B frag
// feeds 2 MFMAs -> B-load count halved vs v1). Optional NSPL column split via
// blockIdx.y. Row-chunked XCD swizzle (gridDim.x divisible by 8).
// EPI: 0 plain(colguard), 4 affine(relu+b+resid, in-place)+s-dot, 6 QP dual-out.
template<int KDIM, int KPAD, int NOUT, int EPI, int NSPL>
__global__ __launch_bounds__(256) void k_mg(
    const float* __restrict__ A, const unsigned short* __restrict__ Wt,
    const float* __restrict__ bias, const float* __restrict__ resid,
    const float* __restrict__ p, float* __restrict__ s_pre,
    float* __restrict__ out, float* __restrict__ out2) {
  constexpr int APITCH = KPAD + 8;
  constexpr int NF = (NOUT + 15) / 16;
  constexpr int NFB = NF / NSPL;
  constexpr int CMAX = (NFB + 3) / 4;
  constexpr int KS = KPAD / 32;
  constexpr int E4 = KDIM / 4;
  constexpr int PADN = KPAD - KDIM;
  __shared__ unsigned short a_sh[32 * APITCH];
  __shared__ float ps_sh[32][4];
  const int tid = threadIdx.x;
  // row-chunked XCD swizzle: XCD x gets contiguous row chunk
  const int g = (blockIdx.x % 8) * (gridDim.x / 8) + blockIdx.x / 8;
  const size_t row0 = (size_t)g * 32;
  const int colbase = blockIdx.y * (NFB * 16);
  for (int i = tid; i < 32 * E4; i += 256) {
    int r = i / E4, c4 = i - r * E4;
    const float4 v = *reinterpret_cast<const float4*>(&A[(row0 + r) * (size_t)KDIM + c4 * 4]);
    unsigned int lo = (unsigned int)f2bf(v.x) | ((unsigned int)f2bf(v.y) << 16);
    unsigned int hi = (unsigned int)f2bf(v.z) | ((unsigned int)f2bf(v.w) << 16);
    *reinterpret_cast<uint2*>(&a_sh[r * APITCH + c4 * 4]) = make_uint2(lo, hi);
  }
  for (int i = tid; i < 32 * PADN; i += 256) {
    int r = i / PADN, c = i - r * PADN;
    a_sh[r * APITCH + KDIM + c] = 0;
  }
  __syncthreads();
  const int lane = tid & 63, w = tid >> 6;
  const int lrow = lane & 15, lk = lane >> 4;
  const int base = (NFB * w) / 4;
  const int cnt = (NFB * (w + 1)) / 4 - base;
  f32x4 acc[2][CMAX];
#pragma unroll
  for (int rg = 0; rg < 2; ++rg)
#pragma unroll
    for (int c = 0; c < CMAX; ++c) acc[rg][c] = f32x4{0.f, 0.f, 0.f, 0.f};
  const unsigned short* ap0 = &a_sh[lrow * APITCH + lk * 8];
  const unsigned short* ap1 = ap0 + 16 * APITCH;
  const unsigned short* wp = &Wt[((size_t)(colbase + base * 16) + lrow) * KPAD + lk * 8];
  for (int ks = 0; ks < KS; ++ks) {
    s16x8 af0 = *reinterpret_cast<const s16x8*>(ap0 + ks * 32);
    s16x8 af1 = *reinterpret_cast<const s16x8*>(ap1 + ks * 32);
#pragma unroll
    for (int c = 0; c < CMAX; ++c) {
      if (c < cnt) {
        s16x8 bf = *reinterpret_cast<const s16x8*>(wp + (size_t)c * 16 * KPAD + ks * 32);
        acc[0][c] = __builtin_amdgcn_mfma_f32_16x16x32_bf16(af0, bf, acc[0][c], 0, 0, 0);
        acc[1][c] = __builtin_amdgcn_mfma_f32_16x16x32_bf16(af1, bf, acc[1][c], 0, 0, 0);
      }
    }
  }
  if (EPI == 0) {
#pragma unroll
    for (int c = 0; c < CMAX; ++c) {
      if (c < cnt) {
        int col = colbase + (base + c) * 16 + lrow;
        if (col < NOUT) {
#pragma unroll
          for (int rg = 0; rg < 2; ++rg)
#pragma unroll
            for (int j = 0; j < 4; ++j)
              out[(row0 + rg * 16 + lk * 4 + j) * (size_t)NOUT + col] = acc[rg][c][j];
        }
      }
    }
  } else if (EPI == 6) {
#pragma unroll
    for (int c = 0; c < CMAX; ++c) {
      if (c < cnt) {
        int col = colbase + (base + c) * 16 + lrow;
        if (col < 200) {
          float bv = bias[col];
#pragma unroll
          for (int rg = 0; rg < 2; ++rg)
#pragma unroll
            for (int j = 0; j < 4; ++j)
              out[(row0 + rg * 16 + lk * 4 + j) * (size_t)AA + col] = acc[rg][c][j] + bv;
        } else if (col >= 208 && col < 608) {
          float bv = bias[col];
#pragma unroll
          for (int rg = 0; rg < 2; ++rg)
#pragma unroll
            for (int j = 0; j < 4; ++j)
              out2[(row0 + rg * 16 + lk * 4 + j) * (size_t)DD + (col - 208)] = acc[rg][c][j] + bv;
        }
      }
    }
  } else {  // EPI == 4
    float spart[2][4];
#pragma unroll
    for (int rg = 0; rg < 2; ++rg)
#pragma unroll
      for (int j = 0; j < 4; ++j) spart[rg][j] = 0.f;
#pragma unroll
    for (int c = 0; c < CMAX; ++c) {
      if (c < cnt) {
        int col = (base + c) * 16 + lrow;
        if (col < NOUT) {
          float bv = bias[col];
#pragma unroll
          for (int rg = 0; rg < 2; ++rg)
#pragma unroll
            for (int j = 0; j < 4; ++j) {
              size_t row = row0 + rg * 16 + lk * 4 + j;
              size_t o = row * (size_t)NOUT + col;
              float v = fmaxf(acc[rg][c][j] + bv, 0.f) + resid[o];
              out[o] = v;
              spart[rg][j] += v * p[(row / CATN) * (size_t)NOUT + col];
            }
        }
      }
    }
#pragma unroll
    for (int rg = 0; rg < 2; ++rg)
#pragma unroll
      for (int j = 0; j < 4; ++j) {
        spart[rg][j] += __shfl_xor(spart[rg][j], 1, 64);
        spart[rg][j] += __shfl_xor(spart[rg][j], 2, 64);
        spart[rg][j] += __shfl_xor(spart[rg][j], 4, 64);
        spart[rg][j] += __shfl_xor(spart[rg][j], 8, 64);
      }
    if (lrow == 0) {
#pragma unroll
      for (int rg = 0; rg < 2; ++rg)
#pragma unroll
        for (int j = 0; j < 4; ++j)
          ps_sh[rg * 16 + lk * 4 + j][w] = spart[rg][j];
    }
    __syncthreads();
    if (tid < 32)
      s_pre[row0 + tid] = (ps_sh[tid][0] + ps_sh[tid][1] + ps_sh[tid][2] + ps_sh[tid][3]) * ATT_INV;
  }
}

// --------- alpha segment-softmax -> P bf16 [b][320 pitch][128]  (b-chunked XCD)
__global__ __launch_bounds__(256) void k_palpha(const float* __restrict__ K,
    const float* __restrict__ Q, const int* __restrict__ cat,
    unsigned short* __restrict__ P) {
  __shared__ float q_sh[AA];
  __shared__ float a_sh[HH];
  __shared__ int c_sh[HH];
  __shared__ float smax[CATN], sden[CATN];
  const int i = blockIdx.x;
  const int xcd = i & 7, s = i >> 3;
  const int b = 8 * xcd + (s >> 4);
  const int n = s & 15;
  const int bn = b * 16 + n;
  const int tid = threadIdx.x;
  if (tid < AA) q_sh[tid] = Q[(size_t)bn * AA + tid];
  if (tid < HH) c_sh[tid] = cat[b * HH + tid];
  __syncthreads();
  if (tid < 2 * HH) {
    int h = tid >> 1, half = tid & 1;
    const float* kp = K + ((size_t)b * HH + h) * AA + half * 100;
    const float* qp = q_sh + half * 100;
    float sv = 0.f;
#pragma unroll 4
    for (int a = 0; a < 100; ++a) sv += kp[a] * qp[a];
    sv += __shfl_xor(sv, 1, 64);
    if (half == 0) a_sh[h] = sv * ATT_INV;
  }
  __syncthreads();
  if (tid < CATN) {
    float m = -3.4e38f;
    for (int h = 0; h < HH; ++h)
      if (c_sh[h] == tid) m = fmaxf(m, a_sh[h]);
    smax[tid] = m;
  }
  __syncthreads();
  if (tid < HH) a_sh[tid] = expf(a_sh[tid] - smax[c_sh[tid]]);
  __syncthreads();
  if (tid < CATN) {
    float dsum = 0.f;
    for (int h = 0; h < HH; ++h)
      if (c_sh[h] == tid) dsum += a_sh[h];
    sden[tid] = dsum;
  }
  __syncthreads();
  if (tid < HH) a_sh[tid] = a_sh[tid] / sden[c_sh[tid]];
  __syncthreads();
  for (int idx = tid; idx < CATN * 128; idx += 256) {
    int c = idx >> 7, h = idx & 127;
    float v = (h < HH && c_sh[h] == c) ? a_sh[h] : 0.f;
    P[((size_t)b * 320 + n * CATN + c) * 128 + h] = f2bf(v);
  }
}

// --------- scatter GEMM: intra[b] = P[b] @ gf[b]  (via gfT); b-chunked XCD
__global__ __launch_bounds__(128) void k_sc(const unsigned short* __restrict__ P,
    const unsigned short* __restrict__ gfT, float* __restrict__ intra) {
  const int i = blockIdx.x;
  const int xcd = i & 7, s = i >> 3;
  const int b = 8 * xcd + s / CATN;
  const int t = s % CATN;
  const int tid = threadIdx.x;
  const int lane = tid & 63, w = tid >> 6;
  const int lrow = lane & 15, lk = lane >> 4;
  const int cbeg = w * 13;
  f32x4 acc[13];
#pragma unroll
  for (int c = 0; c < 13; ++c) acc[c] = f32x4{0.f, 0.f, 0.f, 0.f};
  const unsigned short* ap = &P[((size_t)b * 320 + t * 16 + lrow) * 128 + lk * 8];
  const unsigned short* wp = &gfT[((size_t)b * 416 + cbeg * 16 + lrow) * 128 + lk * 8];
  for (int ks = 0; ks < 4; ++ks) {
    s16x8 af = *reinterpret_cast<const s16x8*>(ap + ks * 32);
#pragma unroll
    for (int c = 0; c < 13; ++c) {
      s16x8 bf = *reinterpret_cast<const s16x8*>(wp + (size_t)c * 16 * 128 + ks * 32);
      acc[c] = __builtin_amdgcn_mfma_f32_16x16x32_bf16(af, bf, acc[c], 0, 0, 0);
    }
  }
  const int r0 = lk * 4;
#pragma unroll
  for (int c = 0; c < 13; ++c) {
    int col = (cbeg + c) * 16 + lrow;
    if (col < DD) {
#pragma unroll
      for (int j = 0; j < 4; ++j)
        intra[((size_t)b * 304 + t * 16 + r0 + j) * (size_t)DD + col] = acc[c][j];
    }
  }
}

// --------- masked softmax over 19 (s_pre precomputed) ; out = sum_c w*intra
__global__ __launch_bounds__(256) void k_final(const float* __restrict__ intra,
    const float* __restrict__ s_pre, const int* __restrict__ mask,
    float* __restrict__ out) {
  __shared__ float w_sh[CATN];
  const int i = blockIdx.x;
  const int xcd = i & 7, s = i >> 3;
  const int b = 8 * xcd + (s >> 4);
  const int n = s & 15;
  const int bn = b * 16 + n;
  const int tid = threadIdx.x;
  if (tid == 0) {
    float sv[CATN];
    float mx = -3.4e38f;
#pragma unroll
    for (int c = 0; c < CATN; ++c) {
      bool mk = (c == CATN - 1) || (mask[b * CATN + c] != 0);
      float sc = mk ? s_pre[bn * CATN + c] : -3.4e38f;
      sv[c] = sc;
      mx = fmaxf(mx, sc);
    }
    float den = 0.f;
#pragma unroll
    for (int c = 0; c < CATN; ++c) {
      float e = (sv[c] <= -3.3e38f) ? 0.f : expf(sv[c] - mx);
      w_sh[c] = e;
      den += e;
    }
    float inv = 1.0f / den;
#pragma unroll
    for (int c = 0; c < CATN; ++c) w_sh[c] *= inv;
  }
  __syncthreads();
  const float* ib = intra + (size_t)bn * CATN * DD;
  for (int d = tid; d < DD; d += 256) {
    float o = 0.f;
#pragma unroll
    for (int c = 0; c < CATN; ++c) o += w_sh[c] * ib[(size_t)c * DD + d];
    out[(size_t)bn * DD + d] = o;
  }
}

// ============================================================================
extern "C" void kernel_launch(void* const* d_in, const int* in_sizes, int n_in,
                              void* d_out, int out_size, void* d_ws, size_t ws_size,
                              hipStream_t stream) {
  const float* hist  = (const float*)d_in[0];
  const float* cand  = (const float*)d_in[1];
  const float* G     = (const float*)d_in[2];
  const int*   cmask = (const int*)d_in[3];
  const int*   cidx  = (const int*)d_in[4];
  const float* proxy = (const float*)d_in[5];
  const float* gW    = (const float*)d_in[6];
  const float* gb    = (const float*)d_in[7];
  const float* lns   = (const float*)d_in[8];
  const float* lnb   = (const float*)d_in[9];
  const float* Kw    = (const float*)d_in[10];
  const float* Qw    = (const float*)d_in[11];
  const float* Qbb   = (const float*)d_in[12];
  const float* afW   = (const float*)d_in[13];
  const float* afb   = (const float*)d_in[14];
  const float* icKw  = (const float*)d_in[15];
  const float* icQw  = (const float*)d_in[16];
  const float* icQb  = (const float*)d_in[17];
  float* out = (float*)d_out;
  float* ws  = (float*)d_ws;

  // ---- workspace layout (float offsets) ----
  // SLOT0 @0: he (3,020,800) -> later {Pbuf us[64][320][128] ; qbuf ; pbuf ; s_pre}
  // SLOT1 @3,020,800: h1/h2 -> Kbuf [6400][200]
  // SLOT2 @6,041,600: tmpb bf16 [7552][416] -> gf fp32 [6400][400]
  // TB    @9,062,400: [64][416][128] bf16
  // intra @10,766,336: [19456][400]
  // wbase @18,548,736 ; bias3 @19,074,560
  float* he    = ws;
  float* s1    = ws + 3020800;
  float* s2f   = ws + 6041600;
  unsigned short* tmpb = (unsigned short*)(ws + 6041600);
  unsigned short* TB   = (unsigned short*)(ws + 9062400);
  float* intra = ws + 10766336;
  unsigned short* wbase = (unsigned short*)(ws + 18548736);
  float* bias3 = ws + 19074560;
  unsigned short* Pbuf = (unsigned short*)ws;
  float* qbuf  = ws + 1310720;                  // [1024][200]
  float* pbuf  = ws + 1515520;                  // [1024][400]
  float* s_pre = ws + 1925120;                  // [19456]
  float* Kbuf  = s1;
  unsigned short* gW0t  = wbase;
  unsigned short* gW1t  = wbase + 173056;
  unsigned short* afWt  = wbase + 346112;
  unsigned short* Kwt   = wbase + 519168;       // [224][416]
  unsigned short* icKwB = wbase + 612352;       // [416][224]
  unsigned short* icQwB = wbase + 705536;       // [416][224]
  unsigned short* Wqp   = wbase + 798720;       // [608][416]

  // 0. weight prep + fused icQ->p matrix
  k_prep_all<<<3461, 256, 0, stream>>>(gW, afW, Kw, Qw, icQw, icKw, Qbb, icQb, wbase, bias3);
  k_prep_M<<<13, 256, 0, stream>>>(icKwB, icQwB, Wqp);
  // 1. he
  k_concat_he<<<(BN * DD + 255) / 256, 256, 0, stream>>>(hist, proxy, he, BN * DD);
  // 2-4. GCN layer 0
  k_toT<NODES><<<448, 256, 0, stream>>>(he, TB);
  k_gmm<<<256, 256, 0, stream>>>(G, TB, tmpb);
  k_mgb_ln<<<BN / 32, 256, 0, stream>>>(tmpb, gW0t, gb, he, lns, lnb, s1);
  // 5-7. GCN layer 1 (in-place s1)
  k_toT<NODES><<<448, 256, 0, stream>>>(s1, TB);
  k_gmm<<<256, 256, 0, stream>>>(G, TB, tmpb);
  k_mgb_ln<<<BN / 32, 256, 0, stream>>>(tmpb, gW1t, gb + DD, s1, lns + DD, lnb + DD, s1);
  // 8. gf compact -> SLOT2
  k_add_gf<<<(BH * DD + 255) / 256, 256, 0, stream>>>(s1, he, s2f, BH * DD);
  // 9. gfT -> TB
  k_toT<HH><<<448, 256, 0, stream>>>(s2f, TB);
  // 10. K = gf @ Kw -> Kbuf   (grid 200 %8==0, b-chunked swizzle)
  k_mg<400, 416, 200, 0, 1><<<BH / 32, 256, 0, stream>>>(s2f, Kwt, nullptr, nullptr, nullptr, nullptr, Kbuf, nullptr);
  // 11. fused Q-proj + p-proj: qbuf / pbuf  (grid 32x2, col-split)
  k_mg<400, 416, 608, 6, 2><<<dim3(BB * NN / 32, 2), 256, 0, stream>>>(cand, Wqp, bias3, nullptr, nullptr, nullptr, qbuf, pbuf);
  // 12. alpha -> P (b-chunked XCD)
  k_palpha<<<BB * NN, 256, 0, stream>>>(Kbuf, qbuf, cidx, Pbuf);
  // 13. intra = P @ gf (MFMA, b-chunked XCD)
  k_sc<<<BB * CATN, 128, 0, stream>>>(Pbuf, TB, intra);
  // 14. affine in-place + fused s-dot (grid 608 %8==0, row-chunked = b-chunked)
  k_mg<400, 416, 400, 4, 1><<<BB * NN * CATN / 32, 256, 0, stream>>>(intra, afWt, afb, intra, pbuf, s_pre, intra, nullptr);
  // 15. final softmax + weighted sum (b-chunked XCD)
  k_final<<<BB * NN, 256, 0, stream>>>(intra, s_pre, cmask, out);
}

// Round 9
// 337.934 us; speedup vs baseline: 1.2297x; 1.1052x over previous
//
#include <hip/hip_runtime.h>
#include <hip/hip_bf16.h>
#include <math.h>

#define BB 64
#define NN 16
#define HH 100
#define DD 400
#define AA 200
#define CATN 19
#define NODES 118            // HH + CATN-1
#define BN (BB*NODES)        // 7552
#define BH (BB*HH)           // 6400
#define ATT_INV 0.07071067811865475f   // 1/sqrt(200)

typedef __attribute__((ext_vector_type(4))) float f32x4;
typedef __attribute__((ext_vector_type(8))) short s16x8;

__device__ __forceinline__ unsigned short f2bf(float f) {
  union { float f; unsigned int u; } v; v.f = f;
  unsigned int r = v.u + 0x7FFFu + ((v.u >> 16) & 1u);
  return (unsigned short)(r >> 16);
}
__device__ __forceinline__ float bf2f(unsigned short u) {
  union { unsigned int i; float f; } v; v.i = ((unsigned int)u) << 16; return v.f;
}

// ---------------- fused concat + transpose: he fp32 + hT bf16 [b][416][128]
__global__ __launch_bounds__(256) void k_toT_he(const float* __restrict__ hist,
    const float* __restrict__ proxy, float* __restrict__ he,
    unsigned short* __restrict__ T) {
  __shared__ float t_sh[64][129];
  const int b = blockIdx.x / 7, dt = blockIdx.x % 7;
  const int d0 = dt * 64;
  const int tid = threadIdx.x;
  const int dc = tid & 63, jr = tid >> 6;
  for (int j0 = 0; j0 < 128; j0 += 4) {
    int j = j0 + jr, d = d0 + dc;
    float v = 0.f;
    if (j < NODES && d < DD) {
      v = (j < HH) ? hist[((size_t)b * HH + j) * DD + d]
                   : proxy[(size_t)(j - HH) * DD + d];
      he[((size_t)b * NODES + j) * DD + d] = v;
    }
    t_sh[dc][j] = v;
  }
  __syncthreads();
  const int jc = tid & 127, dr2 = tid >> 7;
  for (int di = 0; di < 64; di += 2) {
    int dr = di + dr2;
    int d = d0 + dr;
    if (d < 416) T[((size_t)b * 416 + d) * 128 + jc] = f2bf(t_sh[dr][jc]);
  }
}

// ---------------- transpose h[b][RPB][400] fp32 -> T[b][416][128] bf16
template<int RPB>
__global__ __launch_bounds__(256) void k_toT(const float* __restrict__ h,
    unsigned short* __restrict__ T) {
  __shared__ float t_sh[64][129];
  const int b = blockIdx.x / 7, dt = blockIdx.x % 7;
  const int d0 = dt * 64;
  const int tid = threadIdx.x;
  const int dc = tid & 63, jr = tid >> 6;
  for (int j0 = 0; j0 < 128; j0 += 4) {
    int j = j0 + jr, d = d0 + dc;
    float v = (j < RPB && d < DD) ? h[((size_t)b * RPB + j) * DD + d] : 0.f;
    t_sh[dc][j] = v;
  }
  __syncthreads();
  const int jc = tid & 127, dr2 = tid >> 7;
  for (int di = 0; di < 64; di += 2) {
    int dr = di + dr2;
    int d = d0 + dr;
    if (d < 416) T[((size_t)b * 416 + d) * 128 + jc] = f2bf(t_sh[dr][jc]);
  }
}

// ---------------- fused gf = (h2+he)[:, :HH] + transpose -> gf fp32 + gfT bf16
__global__ __launch_bounds__(256) void k_toT_gf(const float* __restrict__ h2,
    const float* __restrict__ he, float* __restrict__ gf,
    unsigned short* __restrict__ T) {
  __shared__ float t_sh[64][129];
  const int b = blockIdx.x / 7, dt = blockIdx.x % 7;
  const int d0 = dt * 64;
  const int tid = threadIdx.x;
  const int dc = tid & 63, jr = tid >> 6;
  for (int j0 = 0; j0 < 128; j0 += 4) {
    int j = j0 + jr, d = d0 + dc;
    float v = 0.f;
    if (j < HH && d < DD) {
      size_t src = ((size_t)b * NODES + j) * DD + d;
      v = h2[src] + he[src];
      gf[((size_t)b * HH + j) * DD + d] = v;
    }
    t_sh[dc][j] = v;
  }
  __syncthreads();
  const int jc = tid & 127, dr2 = tid >> 7;
  for (int di = 0; di < 64; di += 2) {
    int dr = di + dr2;
    int d = d0 + dr;
    if (d < 416) T[((size_t)b * 416 + d) * 128 + jc] = f2bf(t_sh[dr][jc]);
  }
}

// ---------------- graph MFMA: tmpb[b][i][0..415] = bf16( G[b] @ h[b] )
__global__ __launch_bounds__(256) void k_gmm(const float* __restrict__ G,
    const unsigned short* __restrict__ hT, unsigned short* __restrict__ tmpb) {
  __shared__ unsigned short a_sh[32 * 136];
  const int b = blockIdx.x >> 2;
  const int i0 = (blockIdx.x & 3) * 32;
  const int tid = threadIdx.x;
  for (int idx = tid; idx < 32 * 128; idx += 256) {
    int r = idx >> 7, j = idx & 127;
    int i = i0 + r;
    float v = (i < NODES && j < NODES) ? G[((size_t)b * NODES + i) * NODES + j] : 0.f;
    a_sh[r * 136 + j] = f2bf(v);
  }
  __syncthreads();
  const int lane = tid & 63, w = tid >> 6;
  const int lrow = lane & 15, lk = lane >> 4;
  const int rg = w & 1, nh = w >> 1;
  const int cbeg = nh * 13;
  f32x4 acc[13];
#pragma unroll
  for (int c = 0; c < 13; ++c) acc[c] = f32x4{0.f, 0.f, 0.f, 0.f};
  const unsigned short* ap = &a_sh[(rg * 16 + lrow) * 136 + lk * 8];
  const unsigned short* wp = &hT[((size_t)b * 416 + cbeg * 16 + lrow) * 128 + lk * 8];
  for (int ks = 0; ks < 4; ++ks) {
    s16x8 af = *reinterpret_cast<const s16x8*>(ap + ks * 32);
#pragma unroll
    for (int c = 0; c < 13; ++c) {
      s16x8 bf = *reinterpret_cast<const s16x8*>(wp + (size_t)c * 16 * 128 + ks * 32);
      acc[c] = __builtin_amdgcn_mfma_f32_16x16x32_bf16(af, bf, acc[c], 0, 0, 0);
    }
  }
  const int r0 = rg * 16 + lk * 4;
#pragma unroll
  for (int c = 0; c < 13; ++c) {
    int col = (cbeg + c) * 16 + lrow;
#pragma unroll
    for (int j = 0; j < 4; ++j) {
      int i = i0 + r0 + j;
      if (i < NODES)
        tmpb[((size_t)b * NODES + i) * 416 + col] = f2bf(acc[c][j]);
    }
  }
}

// ---------------- dense LN GEMM, bf16 A direct-global: out = LN(relu(A@W+b)+resid)
__global__ __launch_bounds__(256) void k_mgb_ln(
    const unsigned short* __restrict__ A, const unsigned short* __restrict__ Wt,
    const float* __restrict__ bias, const float* __restrict__ resid,
    const float* __restrict__ lns, const float* __restrict__ lnb,
    float* __restrict__ out) {
  __shared__ float ps_sh[32][2][2];
  const int tid = threadIdx.x;
  const size_t row0 = (size_t)blockIdx.x * 32;
  const int lane = tid & 63, w = tid >> 6;
  const int lrow = lane & 15, lk = lane >> 4;
  const int rg = w & 1, nh = w >> 1;
  const int cbeg = nh * 13;
  f32x4 acc[13];
#pragma unroll
  for (int c = 0; c < 13; ++c) acc[c] = f32x4{0.f, 0.f, 0.f, 0.f};
  const unsigned short* ap = &A[(row0 + rg * 16 + lrow) * 416 + lk * 8];
  const unsigned short* wp = &Wt[((size_t)(cbeg * 16) + lrow) * 416 + lk * 8];
  for (int ks = 0; ks < 13; ++ks) {
    s16x8 af = *reinterpret_cast<const s16x8*>(ap + ks * 32);
#pragma unroll
    for (int c = 0; c < 13; ++c) {
      s16x8 bf = *reinterpret_cast<const s16x8*>(wp + (size_t)c * 16 * 416 + ks * 32);
      acc[c] = __builtin_amdgcn_mfma_f32_16x16x32_bf16(af, bf, acc[c], 0, 0, 0);
    }
  }
  const int r0 = rg * 16 + lk * 4;
  float zs[4], zq[4];
#pragma unroll
  for (int j = 0; j < 4; ++j) { zs[j] = 0.f; zq[j] = 0.f; }
#pragma unroll
  for (int c = 0; c < 13; ++c) {
    int col = (cbeg + c) * 16 + lrow;
    bool cv = col < DD;
    float bv = cv ? bias[col] : 0.f;
#pragma unroll
    for (int j = 0; j < 4; ++j) {
      float z = 0.f;
      if (cv)
        z = fmaxf(acc[c][j] + bv, 0.f) + resid[(row0 + r0 + j) * (size_t)DD + col];
      acc[c][j] = z;
      zs[j] += z;
      zq[j] += z * z;
    }
  }
#pragma unroll
  for (int j = 0; j < 4; ++j) {
    zs[j] += __shfl_xor(zs[j], 1, 64); zq[j] += __shfl_xor(zq[j], 1, 64);
    zs[j] += __shfl_xor(zs[j], 2, 64); zq[j] += __shfl_xor(zq[j], 2, 64);
    zs[j] += __shfl_xor(zs[j], 4, 64); zq[j] += __shfl_xor(zq[j], 4, 64);
    zs[j] += __shfl_xor(zs[j], 8, 64); zq[j] += __shfl_xor(zq[j], 8, 64);
  }
  if (lrow == 0) {
#pragma unroll
    for (int j = 0; j < 4; ++j) {
      ps_sh[r0 + j][nh][0] = zs[j];
      ps_sh[r0 + j][nh][1] = zq[j];
    }
  }
  __syncthreads();
  float mu[4], rs[4];
#pragma unroll
  for (int j = 0; j < 4; ++j) {
    float s = ps_sh[r0 + j][0][0] + ps_sh[r0 + j][1][0];
    float q = ps_sh[r0 + j][0][1] + ps_sh[r0 + j][1][1];
    mu[j] = s * (1.0f / DD);
    float var = q * (1.0f / DD) - mu[j] * mu[j];
    rs[j] = 1.0f / sqrtf(var + 1e-5f);
  }
#pragma unroll
  for (int c = 0; c < 13; ++c) {
    int col = (cbeg + c) * 16 + lrow;
    if (col < DD) {
      float sc = lns[col], bo = lnb[col];
#pragma unroll
      for (int j = 0; j < 4; ++j)
        out[(row0 + r0 + j) * (size_t)DD + col] = (acc[c][j] - mu[j]) * rs[j] * sc + bo;
    }
  }
}

// ---------------- one-shot weight prep (bf16 transposed+padded blobs)
// gW0t@0 [416][416], gW1t@173056, afWt@346112, Kwt@519168 [224][416],
// icKwB@612352 [416][224], icQwB@705536 [416][224], Wqp@798720 [608][416]
// bias3 float[608]: 0..199 Qb ; 208..607 pb[d] = icQb . icKw[d,:]
__global__ __launch_bounds__(256) void k_prep_all(const float* __restrict__ gW,
    const float* __restrict__ afW, const float* __restrict__ Kw,
    const float* __restrict__ Qw, const float* __restrict__ icQw,
    const float* __restrict__ icKw, const float* __restrict__ Qb,
    const float* __restrict__ icQb, unsigned short* __restrict__ wbase,
    float* __restrict__ bias3) {
  int idx = blockIdx.x * 256 + threadIdx.x;
  const int SG = 416 * 416;   // 173056
  const int SK = 224 * 416;   // 93184
  if (idx < SG) {             // gW0t
    int n = idx / 416, k = idx - n * 416;
    wbase[idx] = (n < 400 && k < 400) ? f2bf(gW[(size_t)k * 400 + n]) : (unsigned short)0;
    return;
  }
  idx -= SG;
  if (idx < SG) {             // gW1t
    int n = idx / 416, k = idx - n * 416;
    wbase[173056 + idx] = (n < 400 && k < 400) ? f2bf(gW[160000 + (size_t)k * 400 + n]) : (unsigned short)0;
    return;
  }
  idx -= SG;
  if (idx < SG) {             // afWt
    int n = idx / 416, k = idx - n * 416;
    wbase[346112 + idx] = (n < 400 && k < 400) ? f2bf(afW[(size_t)k * 400 + n]) : (unsigned short)0;
    return;
  }
  idx -= SG;
  if (idx < SK) {             // Kwt [224 n][416 k]
    int n = idx / 416, k = idx - n * 416;
    wbase[519168 + idx] = (n < 200 && k < 400) ? f2bf(Kw[(size_t)k * 200 + n]) : (unsigned short)0;
    return;
  }
  idx -= SK;
  if (idx < SK) {             // icKwB [416 d][224 a]
    int d = idx / 224, a = idx - d * 224;
    wbase[612352 + idx] = (d < 400 && a < 200) ? f2bf(icKw[(size_t)d * 200 + a]) : (unsigned short)0;
    return;
  }
  idx -= SK;
  if (idx < SK) {             // icQwB [416 k][224 a]
    int k = idx / 224, a = idx - k * 224;
    wbase[705536 + idx] = (k < 400 && a < 200) ? f2bf(icQw[(size_t)k * 200 + a]) : (unsigned short)0;
    return;
  }
  idx -= SK;
  if (idx < 208 * 416) {      // Wqp rows 0..207 (Q part)
    int n = idx / 416, k = idx - n * 416;
    wbase[798720 + idx] = (n < 200 && k < 400) ? f2bf(Qw[(size_t)k * 200 + n]) : (unsigned short)0;
    return;
  }
  idx -= 208 * 416;
  if (idx < 608) {            // bias3
    float v = 0.f;
    if (idx < 200) v = Qb[idx];
    else if (idx >= 208) {
      const float* kr = icKw + (size_t)(idx - 208) * 200;
      float s = 0.f;
      for (int a = 0; a < 200; ++a) s += icQb[a] * kr[a];
      v = s;
    }
    bias3[idx] = v;
  }
}

// ---------------- M-prep: Wqp[208+d][k] = bf16( sum_a icKw[d,a]*icQw[k,a] ), MFMA
__global__ __launch_bounds__(256) void k_prep_M(const unsigned short* __restrict__ icKwB,
    const unsigned short* __restrict__ icQwB, unsigned short* __restrict__ wqp) {
  const int tid = threadIdx.x;
  const size_t row0 = (size_t)blockIdx.x * 32;
  const int lane = tid & 63, w = tid >> 6;
  const int lrow = lane & 15, lk = lane >> 4;
  const int rg = w & 1, nh = w >> 1;
  const int cbeg = nh * 13;
  f32x4 acc[13];
#pragma unroll
  for (int c = 0; c < 13; ++c) acc[c] = f32x4{0.f, 0.f, 0.f, 0.f};
  const unsigned short* ap = &icKwB[(row0 + rg * 16 + lrow) * 224 + lk * 8];
  const unsigned short* bp = &icQwB[((size_t)(cbeg * 16) + lrow) * 224 + lk * 8];
  for (int ks = 0; ks < 7; ++ks) {
    s16x8 af = *reinterpret_cast<const s16x8*>(ap + ks * 32);
#pragma unroll
    for (int c = 0; c < 13; ++c) {
      s16x8 bf = *reinterpret_cast<const s16x8*>(bp + (size_t)c * 16 * 224 + ks * 32);
      acc[c] = __builtin_amdgcn_mfma_f32_16x16x32_bf16(af, bf, acc[c], 0, 0, 0);
    }
  }
  const int r0 = rg * 16 + lk * 4;
#pragma unroll
  for (int c = 0; c < 13; ++c) {
    int k = (cbeg + c) * 16 + lrow;
#pragma unroll
    for (int j = 0; j < 4; ++j) {
      size_t d = row0 + r0 + j;
      if (d < 400) wqp[(208 + d) * 416 + k] = f2bf(acc[c][j]);
    }
  }
}

// =================== fp32-A MFMA GEMM (v1 decomposition, XCD row-chunk swizzle)
// 4 waves: w&1 = row-group(16), w>>1 = N-half (NF0 frags each). gridDim.x%8==0.
// EPI: 0 plain(colguard), 6 QP dual-output.
template<int KDIM, int KPAD, int NOUT, int EPI>
__global__ __launch_bounds__(256) void k_mg(
    const float* __restrict__ A, const unsigned short* __restrict__ Wt,
    const float* __restrict__ bias, float* __restrict__ out, float* __restrict__ out2) {
  constexpr int APITCH = KPAD + 8;
  constexpr int NF = (NOUT + 15) / 16;
  constexpr int NF0 = (NF + 1) / 2;
  constexpr int KS = KPAD / 32;
  constexpr int E4 = KDIM / 4;
  constexpr int PADN = KPAD - KDIM;
  __shared__ unsigned short a_sh[32 * APITCH];
  const int tid = threadIdx.x;
  const int g = (blockIdx.x % 8) * (gridDim.x / 8) + blockIdx.x / 8;
  const size_t row0 = (size_t)g * 32;
  for (int i = tid; i < 32 * E4; i += 256) {
    int r = i / E4, c4 = i - r * E4;
    const float4 v = *reinterpret_cast<const float4*>(&A[(row0 + r) * (size_t)KDIM + c4 * 4]);
    unsigned int lo = (unsigned int)f2bf(v.x) | ((unsigned int)f2bf(v.y) << 16);
    unsigned int hi = (unsigned int)f2bf(v.z) | ((unsigned int)f2bf(v.w) << 16);
    *reinterpret_cast<uint2*>(&a_sh[r * APITCH + c4 * 4]) = make_uint2(lo, hi);
  }
  for (int i = tid; i < 32 * PADN; i += 256) {
    int r = i / PADN, c = i - r * PADN;
    a_sh[r * APITCH + KDIM + c] = 0;
  }
  __syncthreads();
  const int lane = tid & 63, w = tid >> 6;
  const int lrow = lane & 15, lk = lane >> 4;
  const int rg = w & 1, nh = w >> 1;
  const int cbeg = nh * NF0;
  f32x4 acc[NF0];
#pragma unroll
  for (int c = 0; c < NF0; ++c) acc[c] = f32x4{0.f, 0.f, 0.f, 0.f};
  const unsigned short* ap = &a_sh[(rg * 16 + lrow) * APITCH + lk * 8];
  const unsigned short* wp = &Wt[((size_t)(cbeg * 16) + lrow) * KPAD + lk * 8];
  for (int ks = 0; ks < KS; ++ks) {
    s16x8 af = *reinterpret_cast<const s16x8*>(ap + ks * 32);
#pragma unroll
    for (int c = 0; c < NF0; ++c) {
      s16x8 bf = *reinterpret_cast<const s16x8*>(wp + (size_t)c * 16 * KPAD + ks * 32);
      acc[c] = __builtin_amdgcn_mfma_f32_16x16x32_bf16(af, bf, acc[c], 0, 0, 0);
    }
  }
  const int r0 = rg * 16 + lk * 4;
  if (EPI == 0) {
#pragma unroll
    for (int c = 0; c < NF0; ++c) {
      int col = (cbeg + c) * 16 + lrow;
      if (col < NOUT) {
#pragma unroll
        for (int j = 0; j < 4; ++j)
          out[(row0 + r0 + j) * (size_t)NOUT + col] = acc[c][j];
      }
    }
  } else {  // EPI == 6
#pragma unroll
    for (int c = 0; c < NF0; ++c) {
      int col = (cbeg + c) * 16 + lrow;
      if (col < 200) {
        float bv = bias[col];
#pragma unroll
        for (int j = 0; j < 4; ++j)
          out[(row0 + r0 + j) * (size_t)AA + col] = acc[c][j] + bv;
      } else if (col >= 208 && col < 608) {
        float bv = bias[col];
#pragma unroll
        for (int j = 0; j < 4; ++j)
          out2[(row0 + r0 + j) * (size_t)DD + (col - 208)] = acc[c][j] + bv;
      }
    }
  }
}

// --------- alpha segment-softmax -> P bf16 [b][320 pitch][128]  (b-chunked XCD)
__global__ __launch_bounds__(256) void k_palpha(const float* __restrict__ K,
    const float* __restrict__ Q, const int* __restrict__ cat,
    unsigned short* __restrict__ P) {
  __shared__ float q_sh[AA];
  __shared__ float a_sh[HH];
  __shared__ int c_sh[HH];
  __shared__ float smax[CATN], sden[CATN];
  const int i = blockIdx.x;
  const int xcd = i & 7, s = i >> 3;
  const int b = 8 * xcd + (s >> 4);
  const int n = s & 15;
  const int bn = b * 16 + n;
  const int tid = threadIdx.x;
  if (tid < AA) q_sh[tid] = Q[(size_t)bn * AA + tid];
  if (tid < HH) c_sh[tid] = cat[b * HH + tid];
  __syncthreads();
  if (tid < 2 * HH) {
    int h = tid >> 1, half = tid & 1;
    const float* kp = K + ((size_t)b * HH + h) * AA + half * 100;
    const float* qp = q_sh + half * 100;
    float sv = 0.f;
#pragma unroll 4
    for (int a = 0; a < 100; ++a) sv += kp[a] * qp[a];
    sv += __shfl_xor(sv, 1, 64);
    if (half == 0) a_sh[h] = sv * ATT_INV;
  }
  __syncthreads();
  if (tid < CATN) {
    float m = -3.4e38f;
    for (int h = 0; h < HH; ++h)
      if (c_sh[h] == tid) m = fmaxf(m, a_sh[h]);
    smax[tid] = m;
  }
  __syncthreads();
  if (tid < HH) a_sh[tid] = expf(a_sh[tid] - smax[c_sh[tid]]);
  __syncthreads();
  if (tid < CATN) {
    float dsum = 0.f;
    for (int h = 0; h < HH; ++h)
      if (c_sh[h] == tid) dsum += a_sh[h];
    sden[tid] = dsum;
  }
  __syncthreads();
  if (tid < HH) a_sh[tid] = a_sh[tid] / sden[c_sh[tid]];
  __syncthreads();
  for (int idx = tid; idx < CATN * 128; idx += 256) {
    int c = idx >> 7, h = idx & 127;
    float v = (h < HH && c_sh[h] == c) ? a_sh[h] : 0.f;
    P[((size_t)b * 320 + n * CATN + c) * 128 + h] = f2bf(v);
  }
}

// --------- scatter GEMM -> intraB bf16 [19456][416] (cols>=400 zeroed); b-chunked
__global__ __launch_bounds__(128) void k_sc(const unsigned short* __restrict__ P,
    const unsigned short* __restrict__ gfT, unsigned short* __restrict__ intraB) {
  const int i = blockIdx.x;
  const int xcd = i & 7, s = i >> 3;
  const int b = 8 * xcd + s / CATN;
  const int t = s % CATN;
  const int tid = threadIdx.x;
  const int lane = tid & 63, w = tid >> 6;
  const int lrow = lane & 15, lk = lane >> 4;
  const int cbeg = w * 13;
  f32x4 acc[13];
#pragma unroll
  for (int c = 0; c < 13; ++c) acc[c] = f32x4{0.f, 0.f, 0.f, 0.f};
  const unsigned short* ap = &P[((size_t)b * 320 + t * 16 + lrow) * 128 + lk * 8];
  const unsigned short* wp = &gfT[((size_t)b * 416 + cbeg * 16 + lrow) * 128 + lk * 8];
  for (int ks = 0; ks < 4; ++ks) {
    s16x8 af = *reinterpret_cast<const s16x8*>(ap + ks * 32);
#pragma unroll
    for (int c = 0; c < 13; ++c) {
      s16x8 bf = *reinterpret_cast<const s16x8*>(wp + (size_t)c * 16 * 128 + ks * 32);
      acc[c] = __builtin_amdgcn_mfma_f32_16x16x32_bf16(af, bf, acc[c], 0, 0, 0);
    }
  }
  const int r0 = lk * 4;
#pragma unroll
  for (int c = 0; c < 13; ++c) {
    int col = (cbeg + c) * 16 + lrow;
#pragma unroll
    for (int j = 0; j < 4; ++j)
      intraB[((size_t)b * 304 + t * 16 + r0 + j) * 416 + col] =
          f2bf(col < DD ? acc[c][j] : 0.f);
  }
}

// --------- affine GEMM, bf16 A direct-global (no LDS staging):
// v = relu(A@afW + b) + A ; intra2B = bf16(v) ; s_pre[row] = (v . p[bn]) * ATT_INV
__global__ __launch_bounds__(256) void k_af(
    const unsigned short* __restrict__ A, const unsigned short* __restrict__ Wt,
    const float* __restrict__ bias, const float* __restrict__ p,
    float* __restrict__ s_pre, unsigned short* __restrict__ out2) {
  __shared__ float ps_sh[32][2];
  const int tid = threadIdx.x;
  const int g = (blockIdx.x % 8) * (gridDim.x / 8) + blockIdx.x / 8;
  const size_t row0 = (size_t)g * 32;
  const int lane = tid & 63, w = tid >> 6;
  const int lrow = lane & 15, lk = lane >> 4;
  const int rg = w & 1, nh = w >> 1;
  const int cbeg = nh * 13;
  f32x4 acc[13];
#pragma unroll
  for (int c = 0; c < 13; ++c) acc[c] = f32x4{0.f, 0.f, 0.f, 0.f};
  const unsigned short* ap = &A[(row0 + rg * 16 + lrow) * 416 + lk * 8];
  const unsigned short* wp = &Wt[((size_t)(cbeg * 16) + lrow) * 416 + lk * 8];
  for (int ks = 0; ks < 13; ++ks) {
    s16x8 af = *reinterpret_cast<const s16x8*>(ap + ks * 32);
#pragma unroll
    for (int c = 0; c < 13; ++c) {
      s16x8 bf = *reinterpret_cast<const s16x8*>(wp + (size_t)c * 16 * 416 + ks * 32);
      acc[c] = __builtin_amdgcn_mfma_f32_16x16x32_bf16(af, bf, acc[c], 0, 0, 0);
    }
  }
  const int r0 = rg * 16 + lk * 4;
  const float* prow[4];
#pragma unroll
  for (int j = 0; j < 4; ++j)
    prow[j] = p + (size_t)((row0 + r0 + j) / CATN) * DD;
  float spart[4] = {0.f, 0.f, 0.f, 0.f};
#pragma unroll
  for (int c = 0; c < 13; ++c) {
    int col = (cbeg + c) * 16 + lrow;
    if (col < DD) {
      float bv = bias[col];
#pragma unroll
      for (int j = 0; j < 4; ++j) {
        size_t row = row0 + r0 + j;
        float resid = bf2f(A[row * 416 + col]);
        float v = fmaxf(acc[c][j] + bv, 0.f) + resid;
        out2[row * 416 + col] = f2bf(v);
        spart[j] += v * prow[j][col];
      }
    }
  }
#pragma unroll
  for (int j = 0; j < 4; ++j) {
    spart[j] += __shfl_xor(spart[j], 1, 64);
    spart[j] += __shfl_xor(spart[j], 2, 64);
    spart[j] += __shfl_xor(spart[j], 4, 64);
    spart[j] += __shfl_xor(spart[j], 8, 64);
  }
  if (lrow == 0) {
#pragma unroll
    for (int j = 0; j < 4; ++j) ps_sh[r0 + j][nh] = spart[j];
  }
  __syncthreads();
  if (tid < 32)
    s_pre[row0 + tid] = (ps_sh[tid][0] + ps_sh[tid][1]) * ATT_INV;
}

// --------- masked softmax over 19 (s_pre precomputed) ; out = sum_c w*intra2
__global__ __launch_bounds__(256) void k_final(const unsigned short* __restrict__ intra2B,
    const float* __restrict__ s_pre, const int* __restrict__ mask,
    float* __restrict__ out) {
  __shared__ float w_sh[CATN];
  const int i = blockIdx.x;
  const int xcd = i & 7, s = i >> 3;
  const int b = 8 * xcd + (s >> 4);
  const int n = s & 15;
  const int bn = b * 16 + n;
  const int tid = threadIdx.x;
  if (tid == 0) {
    float sv[CATN];
    float mx = -3.4e38f;
#pragma unroll
    for (int c = 0; c < CATN; ++c) {
      bool mk = (c == CATN - 1) || (mask[b * CATN + c] != 0);
      float sc = mk ? s_pre[bn * CATN + c] : -3.4e38f;
      sv[c] = sc;
      mx = fmaxf(mx, sc);
    }
    float den = 0.f;
#pragma unroll
    for (int c = 0; c < CATN; ++c) {
      float e = (sv[c] <= -3.3e38f) ? 0.f : expf(sv[c] - mx);
      w_sh[c] = e;
      den += e;
    }
    float inv = 1.0f / den;
#pragma unroll
    for (int c = 0; c < CATN; ++c) w_sh[c] *= inv;
  }
  __syncthreads();
  const unsigned short* ib = intra2B + (size_t)bn * CATN * 416;
  for (int d = tid; d < DD; d += 256) {
    float o = 0.f;
#pragma unroll
    for (int c = 0; c < CATN; ++c) o += w_sh[c] * bf2f(ib[c * 416 + d]);
    out[(size_t)bn * DD + d] = o;
  }
}

// ============================================================================
extern "C" void kernel_launch(void* const* d_in, const int* in_sizes, int n_in,
                              void* d_out, int out_size, void* d_ws, size_t ws_size,
                              hipStream_t stream) {
  const float* hist  = (const float*)d_in[0];
  const float* cand  = (const float*)d_in[1];
  const float* G     = (const float*)d_in[2];
  const int*   cmask = (const int*)d_in[3];
  const int*   cidx  = (const int*)d_in[4];
  const float* proxy = (const float*)d_in[5];
  const float* gW    = (const float*)d_in[6];
  const float* gb    = (const float*)d_in[7];
  const float* lns   = (const float*)d_in[8];
  const float* lnb   = (const float*)d_in[9];
  const float* Kw    = (const float*)d_in[10];
  const float* Qw    = (const float*)d_in[11];
  const float* Qbb   = (const float*)d_in[12];
  const float* afW   = (const float*)d_in[13];
  const float* afb   = (const float*)d_in[14];
  const float* icKw  = (const float*)d_in[15];
  const float* icQw  = (const float*)d_in[16];
  const float* icQb  = (const float*)d_in[17];
  float* out = (float*)d_out;
  float* ws  = (float*)d_ws;

  // ---- workspace layout (float offsets) ----
  // he      @0          3,020,800  (-> Pbuf/qbuf/pbuf/s_pre after toT_gf)
  // s1      @3,020,800  3,020,800  (h1/h2 -> Kbuf)
  // s2f     @6,041,600  3,020,800  (tmpb bf16 [7552][416] -> gf fp32 [6400][400])
  // TB      @9,062,400  1,703,936  ([64][416][128] bf16)
  // intraB  @10,766,336 4,046,848  (bf16 [19456][416])
  // intra2B @14,813,184 4,046,848  (bf16 [19456][416])
  // wbase   @18,860,032   525,824 ; bias3 @19,385,856 (608)   total 19,386,464
  float* he    = ws;
  float* s1    = ws + 3020800;
  float* s2f   = ws + 6041600;
  unsigned short* tmpb   = (unsigned short*)(ws + 6041600);
  unsigned short* TB     = (unsigned short*)(ws + 9062400);
  unsigned short* intraB = (unsigned short*)(ws + 10766336);
  unsigned short* intra2B= (unsigned short*)(ws + 14813184);
  unsigned short* wbase  = (unsigned short*)(ws + 18860032);
  float* bias3 = ws + 19385856;
  unsigned short* Pbuf = (unsigned short*)ws;
  float* qbuf  = ws + 1310720;                  // [1024][200]
  float* pbuf  = ws + 1515520;                  // [1024][400]
  float* s_pre = ws + 1925120;                  // [19456]
  float* Kbuf  = s1;
  unsigned short* gW0t  = wbase;
  unsigned short* gW1t  = wbase + 173056;
  unsigned short* afWt  = wbase + 346112;
  unsigned short* Kwt   = wbase + 519168;       // [224][416]
  unsigned short* icKwB = wbase + 612352;       // [416][224]
  unsigned short* icQwB = wbase + 705536;       // [416][224]
  unsigned short* Wqp   = wbase + 798720;       // [608][416]

  // 0. weight prep + fused icQ->p matrix
  k_prep_all<<<3461, 256, 0, stream>>>(gW, afW, Kw, Qw, icQw, icKw, Qbb, icQb, wbase, bias3);
  k_prep_M<<<13, 256, 0, stream>>>(icKwB, icQwB, Wqp);
  // 1. fused concat + transpose: he + hT
  k_toT_he<<<448, 256, 0, stream>>>(hist, proxy, he, TB);
  // 2-3. GCN layer 0
  k_gmm<<<256, 256, 0, stream>>>(G, TB, tmpb);
  k_mgb_ln<<<BN / 32, 256, 0, stream>>>(tmpb, gW0t, gb, he, lns, lnb, s1);
  // 4-6. GCN layer 1 (in-place s1)
  k_toT<NODES><<<448, 256, 0, stream>>>(s1, TB);
  k_gmm<<<256, 256, 0, stream>>>(G, TB, tmpb);
  k_mgb_ln<<<BN / 32, 256, 0, stream>>>(tmpb, gW1t, gb + DD, s1, lns + DD, lnb + DD, s1);
  // 7. fused gf = (h2+he)[:, :HH] + transpose: gf + gfT
  k_toT_gf<<<448, 256, 0, stream>>>(s1, he, s2f, TB);
  // 8. K = gf @ Kw -> Kbuf (grid 200 %8==0)
  k_mg<400, 416, 200, 0><<<BH / 32, 256, 0, stream>>>(s2f, Kwt, nullptr, Kbuf, nullptr);
  // 9. fused Q-proj + p-proj (grid 32 %8==0)
  k_mg<400, 416, 608, 6><<<BB * NN / 32, 256, 0, stream>>>(cand, Wqp, bias3, qbuf, pbuf);
  // 10. alpha -> P (b-chunked XCD)
  k_palpha<<<BB * NN, 256, 0, stream>>>(Kbuf, qbuf, cidx, Pbuf);
  // 11. intra = P @ gf -> intraB bf16 (b-chunked XCD)
  k_sc<<<BB * CATN, 128, 0, stream>>>(Pbuf, TB, intraB);
  // 12. affine (direct bf16 A, no LDS) + fused s-dot -> intra2B, s_pre
  k_af<<<BB * NN * CATN / 32, 256, 0, stream>>>(intraB, afWt, afb, pbuf, s_pre, intra2B);
  // 13. final softmax + weighted sum (b-chunked XCD)
  k_final<<<BB * NN, 256, 0, stream>>>(intra2B, s_pre, cmask, out);
}

// Round 10
// 332.076 us; speedup vs baseline: 1.2514x; 1.0176x over previous
//
#include <hip/hip_runtime.h>
#include <hip/hip_bf16.h>
#include <math.h>

#define BB 64
#define NN 16
#define HH 100
#define DD 400
#define AA 200
#define CATN 19
#define NODES 118            // HH + CATN-1
#define BN (BB*NODES)        // 7552
#define BH (BB*HH)           // 6400
#define ATT_INV 0.07071067811865475f   // 1/sqrt(200)

typedef __attribute__((ext_vector_type(4))) float f32x4;
typedef __attribute__((ext_vector_type(8))) short s16x8;

__device__ __forceinline__ unsigned short f2bf(float f) {
  union { float f; unsigned int u; } v; v.f = f;
  unsigned int r = v.u + 0x7FFFu + ((v.u >> 16) & 1u);
  return (unsigned short)(r >> 16);
}
__device__ __forceinline__ float bf2f(unsigned short u) {
  union { unsigned int i; float f; } v; v.i = ((unsigned int)u) << 16; return v.f;
}

// ---------------- fused concat + transpose: he fp32 + hT bf16 [b][416][128]
__global__ __launch_bounds__(256) void k_toT_he(const float* __restrict__ hist,
    const float* __restrict__ proxy, float* __restrict__ he,
    unsigned short* __restrict__ T) {
  __shared__ float t_sh[64][129];
  const int b = blockIdx.x / 7, dt = blockIdx.x % 7;
  const int d0 = dt * 64;
  const int tid = threadIdx.x;
  const int dc = tid & 63, jr = tid >> 6;
  for (int j0 = 0; j0 < 128; j0 += 4) {
    int j = j0 + jr, d = d0 + dc;
    float v = 0.f;
    if (j < NODES && d < DD) {
      v = (j < HH) ? hist[((size_t)b * HH + j) * DD + d]
                   : proxy[(size_t)(j - HH) * DD + d];
      he[((size_t)b * NODES + j) * DD + d] = v;
    }
    t_sh[dc][j] = v;
  }
  __syncthreads();
  const int jc = tid & 127, dr2 = tid >> 7;
  for (int di = 0; di < 64; di += 2) {
    int dr = di + dr2;
    int d = d0 + dr;
    if (d < 416) T[((size_t)b * 416 + d) * 128 + jc] = f2bf(t_sh[dr][jc]);
  }
}

// ---------------- transpose h[b][RPB][400] fp32 -> T[b][416][128] bf16
template<int RPB>
__global__ __launch_bounds__(256) void k_toT(const float* __restrict__ h,
    unsigned short* __restrict__ T) {
  __shared__ float t_sh[64][129];
  const int b = blockIdx.x / 7, dt = blockIdx.x % 7;
  const int d0 = dt * 64;
  const int tid = threadIdx.x;
  const int dc = tid & 63, jr = tid >> 6;
  for (int j0 = 0; j0 < 128; j0 += 4) {
    int j = j0 + jr, d = d0 + dc;
    float v = (j < RPB && d < DD) ? h[((size_t)b * RPB + j) * DD + d] : 0.f;
    t_sh[dc][j] = v;
  }
  __syncthreads();
  const int jc = tid & 127, dr2 = tid >> 7;
  for (int di = 0; di < 64; di += 2) {
    int dr = di + dr2;
    int d = d0 + dr;
    if (d < 416) T[((size_t)b * 416 + d) * 128 + jc] = f2bf(t_sh[dr][jc]);
  }
}

// ---------------- fused gf = (h2+he)[:, :HH] + transpose -> gf fp32 + gfT bf16
__global__ __launch_bounds__(256) void k_toT_gf(const float* __restrict__ h2,
    const float* __restrict__ he, float* __restrict__ gf,
    unsigned short* __restrict__ T) {
  __shared__ float t_sh[64][129];
  const int b = blockIdx.x / 7, dt = blockIdx.x % 7;
  const int d0 = dt * 64;
  const int tid = threadIdx.x;
  const int dc = tid & 63, jr = tid >> 6;
  for (int j0 = 0; j0 < 128; j0 += 4) {
    int j = j0 + jr, d = d0 + dc;
    float v = 0.f;
    if (j < HH && d < DD) {
      size_t src = ((size_t)b * NODES + j) * DD + d;
      v = h2[src] + he[src];
      gf[((size_t)b * HH + j) * DD + d] = v;
    }
    t_sh[dc][j] = v;
  }
  __syncthreads();
  const int jc = tid & 127, dr2 = tid >> 7;
  for (int di = 0; di < 64; di += 2) {
    int dr = di + dr2;
    int d = d0 + dr;
    if (d < 416) T[((size_t)b * 416 + d) * 128 + jc] = f2bf(t_sh[dr][jc]);
  }
}

// ---------------- graph MFMA: tmpb[b][i][0..415] = bf16( G[b] @ h[b] )
__global__ __launch_bounds__(256) void k_gmm(const float* __restrict__ G,
    const unsigned short* __restrict__ hT, unsigned short* __restrict__ tmpb) {
  __shared__ unsigned short a_sh[32 * 136];
  const int b = blockIdx.x >> 2;
  const int i0 = (blockIdx.x & 3) * 32;
  const int tid = threadIdx.x;
  for (int idx = tid; idx < 32 * 128; idx += 256) {
    int r = idx >> 7, j = idx & 127;
    int i = i0 + r;
    float v = (i < NODES && j < NODES) ? G[((size_t)b * NODES + i) * NODES + j] : 0.f;
    a_sh[r * 136 + j] = f2bf(v);
  }
  __syncthreads();
  const int lane = tid & 63, w = tid >> 6;
  const int lrow = lane & 15, lk = lane >> 4;
  const int rg = w & 1, nh = w >> 1;
  const int cbeg = nh * 13;
  f32x4 acc[13];
#pragma unroll
  for (int c = 0; c < 13; ++c) acc[c] = f32x4{0.f, 0.f, 0.f, 0.f};
  const unsigned short* ap = &a_sh[(rg * 16 + lrow) * 136 + lk * 8];
  const unsigned short* wp = &hT[((size_t)b * 416 + cbeg * 16 + lrow) * 128 + lk * 8];
  for (int ks = 0; ks < 4; ++ks) {
    s16x8 af = *reinterpret_cast<const s16x8*>(ap + ks * 32);
#pragma unroll
    for (int c = 0; c < 13; ++c) {
      s16x8 bf = *reinterpret_cast<const s16x8*>(wp + (size_t)c * 16 * 128 + ks * 32);
      acc[c] = __builtin_amdgcn_mfma_f32_16x16x32_bf16(af, bf, acc[c], 0, 0, 0);
    }
  }
  const int r0 = rg * 16 + lk * 4;
#pragma unroll
  for (int c = 0; c < 13; ++c) {
    int col = (cbeg + c) * 16 + lrow;
#pragma unroll
    for (int j = 0; j < 4; ++j) {
      int i = i0 + r0 + j;
      if (i < NODES)
        tmpb[((size_t)b * NODES + i) * 416 + col] = f2bf(acc[c][j]);
    }
  }
}

// ---------------- dense LN GEMM, bf16 A direct-global: out = LN(relu(A@W+b)+resid)
__global__ __launch_bounds__(256) void k_mgb_ln(
    const unsigned short* __restrict__ A, const unsigned short* __restrict__ Wt,
    const float* __restrict__ bias, const float* __restrict__ resid,
    const float* __restrict__ lns, const float* __restrict__ lnb,
    float* __restrict__ out) {
  __shared__ float ps_sh[32][2][2];
  const int tid = threadIdx.x;
  const size_t row0 = (size_t)blockIdx.x * 32;
  const int lane = tid & 63, w = tid >> 6;
  const int lrow = lane & 15, lk = lane >> 4;
  const int rg = w & 1, nh = w >> 1;
  const int cbeg = nh * 13;
  f32x4 acc[13];
#pragma unroll
  for (int c = 0; c < 13; ++c) acc[c] = f32x4{0.f, 0.f, 0.f, 0.f};
  const unsigned short* ap = &A[(row0 + rg * 16 + lrow) * 416 + lk * 8];
  const unsigned short* wp = &Wt[((size_t)(cbeg * 16) + lrow) * 416 + lk * 8];
  for (int ks = 0; ks < 13; ++ks) {
    s16x8 af = *reinterpret_cast<const s16x8*>(ap + ks * 32);
#pragma unroll
    for (int c = 0; c < 13; ++c) {
      s16x8 bf = *reinterpret_cast<const s16x8*>(wp + (size_t)c * 16 * 416 + ks * 32);
      acc[c] = __builtin_amdgcn_mfma_f32_16x16x32_bf16(af, bf, acc[c], 0, 0, 0);
    }
  }
  const int r0 = rg * 16 + lk * 4;
  float zs[4], zq[4];
#pragma unroll
  for (int j = 0; j < 4; ++j) { zs[j] = 0.f; zq[j] = 0.f; }
#pragma unroll
  for (int c = 0; c < 13; ++c) {
    int col = (cbeg + c) * 16 + lrow;
    bool cv = col < DD;
    float bv = cv ? bias[col] : 0.f;
#pragma unroll
    for (int j = 0; j < 4; ++j) {
      float z = 0.f;
      if (cv)
        z = fmaxf(acc[c][j] + bv, 0.f) + resid[(row0 + r0 + j) * (size_t)DD + col];
      acc[c][j] = z;
      zs[j] += z;
      zq[j] += z * z;
    }
  }
#pragma unroll
  for (int j = 0; j < 4; ++j) {
    zs[j] += __shfl_xor(zs[j], 1, 64); zq[j] += __shfl_xor(zq[j], 1, 64);
    zs[j] += __shfl_xor(zs[j], 2, 64); zq[j] += __shfl_xor(zq[j], 2, 64);
    zs[j] += __shfl_xor(zs[j], 4, 64); zq[j] += __shfl_xor(zq[j], 4, 64);
    zs[j] += __shfl_xor(zs[j], 8, 64); zq[j] += __shfl_xor(zq[j], 8, 64);
  }
  if (lrow == 0) {
#pragma unroll
    for (int j = 0; j < 4; ++j) {
      ps_sh[r0 + j][nh][0] = zs[j];
      ps_sh[r0 + j][nh][1] = zq[j];
    }
  }
  __syncthreads();
  float mu[4], rs[4];
#pragma unroll
  for (int j = 0; j < 4; ++j) {
    float s = ps_sh[r0 + j][0][0] + ps_sh[r0 + j][1][0];
    float q = ps_sh[r0 + j][0][1] + ps_sh[r0 + j][1][1];
    mu[j] = s * (1.0f / DD);
    float var = q * (1.0f / DD) - mu[j] * mu[j];
    rs[j] = 1.0f / sqrtf(var + 1e-5f);
  }
#pragma unroll
  for (int c = 0; c < 13; ++c) {
    int col = (cbeg + c) * 16 + lrow;
    if (col < DD) {
      float sc = lns[col], bo = lnb[col];
#pragma unroll
      for (int j = 0; j < 4; ++j)
        out[(row0 + r0 + j) * (size_t)DD + col] = (acc[c][j] - mu[j]) * rs[j] * sc + bo;
    }
  }
}

// ---------------- one-shot weight prep (bf16 transposed+padded blobs)
__global__ __launch_bounds__(256) void k_prep_all(const float* __restrict__ gW,
    const float* __restrict__ afW, const float* __restrict__ Kw,
    const float* __restrict__ Qw, const float* __restrict__ icQw,
    const float* __restrict__ icKw, const float* __restrict__ Qb,
    const float* __restrict__ icQb, unsigned short* __restrict__ wbase,
    float* __restrict__ bias3) {
  int idx = blockIdx.x * 256 + threadIdx.x;
  const int SG = 416 * 416;   // 173056
  const int SK = 224 * 416;   // 93184
  if (idx < SG) {             // gW0t
    int n = idx / 416, k = idx - n * 416;
    wbase[idx] = (n < 400 && k < 400) ? f2bf(gW[(size_t)k * 400 + n]) : (unsigned short)0;
    return;
  }
  idx -= SG;
  if (idx < SG) {             // gW1t
    int n = idx / 416, k = idx - n * 416;
    wbase[173056 + idx] = (n < 400 && k < 400) ? f2bf(gW[160000 + (size_t)k * 400 + n]) : (unsigned short)0;
    return;
  }
  idx -= SG;
  if (idx < SG) {             // afWt
    int n = idx / 416, k = idx - n * 416;
    wbase[346112 + idx] = (n < 400 && k < 400) ? f2bf(afW[(size_t)k * 400 + n]) : (unsigned short)0;
    return;
  }
  idx -= SG;
  if (idx < SK) {             // Kwt [224 n][416 k]
    int n = idx / 416, k = idx - n * 416;
    wbase[519168 + idx] = (n < 200 && k < 400) ? f2bf(Kw[(size_t)k * 200 + n]) : (unsigned short)0;
    return;
  }
  idx -= SK;
  if (idx < SK) {             // icKwB [416 d][224 a]
    int d = idx / 224, a = idx - d * 224;
    wbase[612352 + idx] = (d < 400 && a < 200) ? f2bf(icKw[(size_t)d * 200 + a]) : (unsigned short)0;
    return;
  }
  idx -= SK;
  if (idx < SK) {             // icQwB [416 k][224 a]
    int k = idx / 224, a = idx - k * 224;
    wbase[705536 + idx] = (k < 400 && a < 200) ? f2bf(icQw[(size_t)k * 200 + a]) : (unsigned short)0;
    return;
  }
  idx -= SK;
  if (idx < 208 * 416) {      // Wqp rows 0..207 (Q part)
    int n = idx / 416, k = idx - n * 416;
    wbase[798720 + idx] = (n < 200 && k < 400) ? f2bf(Qw[(size_t)k * 200 + n]) : (unsigned short)0;
    return;
  }
  idx -= 208 * 416;
  if (idx < 608) {            // bias3
    float v = 0.f;
    if (idx < 200) v = Qb[idx];
    else if (idx >= 208) {
      const float* kr = icKw + (size_t)(idx - 208) * 200;
      float s = 0.f;
      for (int a = 0; a < 200; ++a) s += icQb[a] * kr[a];
      v = s;
    }
    bias3[idx] = v;
  }
}

// ---------------- M-prep: Wqp[208+d][k] = bf16( sum_a icKw[d,a]*icQw[k,a] ), MFMA
__global__ __launch_bounds__(256) void k_prep_M(const unsigned short* __restrict__ icKwB,
    const unsigned short* __restrict__ icQwB, unsigned short* __restrict__ wqp) {
  const int tid = threadIdx.x;
  const size_t row0 = (size_t)blockIdx.x * 32;
  const int lane = tid & 63, w = tid >> 6;
  const int lrow = lane & 15, lk = lane >> 4;
  const int rg = w & 1, nh = w >> 1;
  const int cbeg = nh * 13;
  f32x4 acc[13];
#pragma unroll
  for (int c = 0; c < 13; ++c) acc[c] = f32x4{0.f, 0.f, 0.f, 0.f};
  const unsigned short* ap = &icKwB[(row0 + rg * 16 + lrow) * 224 + lk * 8];
  const unsigned short* bp = &icQwB[((size_t)(cbeg * 16) + lrow) * 224 + lk * 8];
  for (int ks = 0; ks < 7; ++ks) {
    s16x8 af = *reinterpret_cast<const s16x8*>(ap + ks * 32);
#pragma unroll
    for (int c = 0; c < 13; ++c) {
      s16x8 bf = *reinterpret_cast<const s16x8*>(bp + (size_t)c * 16 * 224 + ks * 32);
      acc[c] = __builtin_amdgcn_mfma_f32_16x16x32_bf16(af, bf, acc[c], 0, 0, 0);
    }
  }
  const int r0 = rg * 16 + lk * 4;
#pragma unroll
  for (int c = 0; c < 13; ++c) {
    int k = (cbeg + c) * 16 + lrow;
#pragma unroll
    for (int j = 0; j < 4; ++j) {
      size_t d = row0 + r0 + j;
      if (d < 400) wqp[(208 + d) * 416 + k] = f2bf(acc[c][j]);
    }
  }
}

// =================== fp32-A MFMA GEMM (v1 decomposition, XCD row-chunk swizzle)
// EPI: 0 plain(colguard), 6 QP dual-output.
template<int KDIM, int KPAD, int NOUT, int EPI>
__global__ __launch_bounds__(256) void k_mg(
    const float* __restrict__ A, const unsigned short* __restrict__ Wt,
    const float* __restrict__ bias, float* __restrict__ out, float* __restrict__ out2) {
  constexpr int APITCH = KPAD + 8;
  constexpr int NF = (NOUT + 15) / 16;
  constexpr int NF0 = (NF + 1) / 2;
  constexpr int KS = KPAD / 32;
  constexpr int E4 = KDIM / 4;
  constexpr int PADN = KPAD - KDIM;
  __shared__ unsigned short a_sh[32 * APITCH];
  const int tid = threadIdx.x;
  const int g = (blockIdx.x % 8) * (gridDim.x / 8) + blockIdx.x / 8;
  const size_t row0 = (size_t)g * 32;
  for (int i = tid; i < 32 * E4; i += 256) {
    int r = i / E4, c4 = i - r * E4;
    const float4 v = *reinterpret_cast<const float4*>(&A[(row0 + r) * (size_t)KDIM + c4 * 4]);
    unsigned int lo = (unsigned int)f2bf(v.x) | ((unsigned int)f2bf(v.y) << 16);
    unsigned int hi = (unsigned int)f2bf(v.z) | ((unsigned int)f2bf(v.w) << 16);
    *reinterpret_cast<uint2*>(&a_sh[r * APITCH + c4 * 4]) = make_uint2(lo, hi);
  }
  for (int i = tid; i < 32 * PADN; i += 256) {
    int r = i / PADN, c = i - r * PADN;
    a_sh[r * APITCH + KDIM + c] = 0;
  }
  __syncthreads();
  const int lane = tid & 63, w = tid >> 6;
  const int lrow = lane & 15, lk = lane >> 4;
  const int rg = w & 1, nh = w >> 1;
  const int cbeg = nh * NF0;
  f32x4 acc[NF0];
#pragma unroll
  for (int c = 0; c < NF0; ++c) acc[c] = f32x4{0.f, 0.f, 0.f, 0.f};
  const unsigned short* ap = &a_sh[(rg * 16 + lrow) * APITCH + lk * 8];
  const unsigned short* wp = &Wt[((size_t)(cbeg * 16) + lrow) * KPAD + lk * 8];
  for (int ks = 0; ks < KS; ++ks) {
    s16x8 af = *reinterpret_cast<const s16x8*>(ap + ks * 32);
#pragma unroll
    for (int c = 0; c < NF0; ++c) {
      s16x8 bf = *reinterpret_cast<const s16x8*>(wp + (size_t)c * 16 * KPAD + ks * 32);
      acc[c] = __builtin_amdgcn_mfma_f32_16x16x32_bf16(af, bf, acc[c], 0, 0, 0);
    }
  }
  const int r0 = rg * 16 + lk * 4;
  if (EPI == 0) {
#pragma unroll
    for (int c = 0; c < NF0; ++c) {
      int col = (cbeg + c) * 16 + lrow;
      if (col < NOUT) {
#pragma unroll
        for (int j = 0; j < 4; ++j)
          out[(row0 + r0 + j) * (size_t)NOUT + col] = acc[c][j];
      }
    }
  } else {  // EPI == 6
#pragma unroll
    for (int c = 0; c < NF0; ++c) {
      int col = (cbeg + c) * 16 + lrow;
      if (col < 200) {
        float bv = bias[col];
#pragma unroll
        for (int j = 0; j < 4; ++j)
          out[(row0 + r0 + j) * (size_t)AA + col] = acc[c][j] + bv;
      } else if (col >= 208 && col < 608) {
        float bv = bias[col];
#pragma unroll
        for (int j = 0; j < 4; ++j)
          out2[(row0 + r0 + j) * (size_t)DD + (col - 208)] = acc[c][j] + bv;
      }
    }
  }
}

// --------- alpha segment-softmax -> P bf16 [b][320 pitch][128]  (b-chunked XCD)
__global__ __launch_bounds__(256) void k_palpha(const float* __restrict__ K,
    const float* __restrict__ Q, const int* __restrict__ cat,
    unsigned short* __restrict__ P) {
  __shared__ float q_sh[AA];
  __shared__ float a_sh[HH];
  __shared__ int c_sh[HH];
  __shared__ float smax[CATN], sden[CATN];
  const int i = blockIdx.x;
  const int xcd = i & 7, s = i >> 3;
  const int b = 8 * xcd + (s >> 4);
  const int n = s & 15;
  const int bn = b * 16 + n;
  const int tid = threadIdx.x;
  if (tid < AA) q_sh[tid] = Q[(size_t)bn * AA + tid];
  if (tid < HH) c_sh[tid] = cat[b * HH + tid];
  __syncthreads();
  if (tid < 2 * HH) {
    int h = tid >> 1, half = tid & 1;
    const float* kp = K + ((size_t)b * HH + h) * AA + half * 100;
    const float* qp = q_sh + half * 100;
    float sv = 0.f;
#pragma unroll 4
    for (int a = 0; a < 100; ++a) sv += kp[a] * qp[a];
    sv += __shfl_xor(sv, 1, 64);
    if (half == 0) a_sh[h] = sv * ATT_INV;
  }
  __syncthreads();
  if (tid < CATN) {
    float m = -3.4e38f;
    for (int h = 0; h < HH; ++h)
      if (c_sh[h] == tid) m = fmaxf(m, a_sh[h]);
    smax[tid] = m;
  }
  __syncthreads();
  if (tid < HH) a_sh[tid] = expf(a_sh[tid] - smax[c_sh[tid]]);
  __syncthreads();
  if (tid < CATN) {
    float dsum = 0.f;
    for (int h = 0; h < HH; ++h)
      if (c_sh[h] == tid) dsum += a_sh[h];
    sden[tid] = dsum;
  }
  __syncthreads();
  if (tid < HH) a_sh[tid] = a_sh[tid] / sden[c_sh[tid]];
  __syncthreads();
  for (int idx = tid; idx < CATN * 128; idx += 256) {
    int c = idx >> 7, h = idx & 127;
    float v = (h < HH && c_sh[h] == c) ? a_sh[h] : 0.f;
    P[((size_t)b * 320 + n * CATN + c) * 128 + h] = f2bf(v);
  }
}

// --------- scatter GEMM -> intraB bf16 [19456][416] (cols>=400 zeroed); b-chunked
__global__ __launch_bounds__(128) void k_sc(const unsigned short* __restrict__ P,
    const unsigned short* __restrict__ gfT, unsigned short* __restrict__ intraB) {
  const int i = blockIdx.x;
  const int xcd = i & 7, s = i >> 3;
  const int b = 8 * xcd + s / CATN;
  const int t = s % CATN;
  const int tid = threadIdx.x;
  const int lane = tid & 63, w = tid >> 6;
  const int lrow = lane & 15, lk = lane >> 4;
  const int cbeg = w * 13;
  f32x4 acc[13];
#pragma unroll
  for (int c = 0; c < 13; ++c) acc[c] = f32x4{0.f, 0.f, 0.f, 0.f};
  const unsigned short* ap = &P[((size_t)b * 320 + t * 16 + lrow) * 128 + lk * 8];
  const unsigned short* wp = &gfT[((size_t)b * 416 + cbeg * 16 + lrow) * 128 + lk * 8];
  for (int ks = 0; ks < 4; ++ks) {
    s16x8 af = *reinterpret_cast<const s16x8*>(ap + ks * 32);
#pragma unroll
    for (int c = 0; c < 13; ++c) {
      s16x8 bf = *reinterpret_cast<const s16x8*>(wp + (size_t)c * 16 * 128 + ks * 32);
      acc[c] = __builtin_amdgcn_mfma_f32_16x16x32_bf16(af, bf, acc[c], 0, 0, 0);
    }
  }
  const int r0 = lk * 4;
#pragma unroll
  for (int c = 0; c < 13; ++c) {
    int col = (cbeg + c) * 16 + lrow;
#pragma unroll
    for (int j = 0; j < 4; ++j)
      intraB[((size_t)b * 304 + t * 16 + r0 + j) * 416 + col] =
          f2bf(col < DD ? acc[c][j] : 0.f);
  }
}

// --------- affine GEMM v3: 64-row tiles, dual row-group per wave (B reuse 2x).
// 4 waves: rgp = w&1 (rows rgp*16..+15 and +32), nh = w>>1 (13 frags).
// bf16 A direct-global; v = relu(A@afW+b)+A ; intra2B = bf16(v) ;
// s_pre[row] = (v . p[row/19]) * ATT_INV
__global__ __launch_bounds__(256) void k_af64(
    const unsigned short* __restrict__ A, const unsigned short* __restrict__ Wt,
    const float* __restrict__ bias, const float* __restrict__ p,
    float* __restrict__ s_pre, unsigned short* __restrict__ out2) {
  __shared__ float ps_sh[64][2];
  const int tid = threadIdx.x;
  const int g = (blockIdx.x % 8) * (gridDim.x / 8) + blockIdx.x / 8;
  const size_t row0 = (size_t)g * 64;
  const int lane = tid & 63, w = tid >> 6;
  const int lrow = lane & 15, lk = lane >> 4;
  const int rgp = w & 1, nh = w >> 1;
  const int cbeg = nh * 13;
  f32x4 acc0[13], acc1[13];
#pragma unroll
  for (int c = 0; c < 13; ++c) {
    acc0[c] = f32x4{0.f, 0.f, 0.f, 0.f};
    acc1[c] = f32x4{0.f, 0.f, 0.f, 0.f};
  }
  const unsigned short* ap0 = &A[(row0 + rgp * 16 + lrow) * 416 + lk * 8];
  const unsigned short* ap1 = ap0 + 32 * 416;
  const unsigned short* wp = &Wt[((size_t)(cbeg * 16) + lrow) * 416 + lk * 8];
  for (int ks = 0; ks < 13; ++ks) {
    s16x8 af0 = *reinterpret_cast<const s16x8*>(ap0 + ks * 32);
    s16x8 af1 = *reinterpret_cast<const s16x8*>(ap1 + ks * 32);
#pragma unroll
    for (int c = 0; c < 13; ++c) {
      s16x8 bf = *reinterpret_cast<const s16x8*>(wp + (size_t)c * 16 * 416 + ks * 32);
      acc0[c] = __builtin_amdgcn_mfma_f32_16x16x32_bf16(af0, bf, acc0[c], 0, 0, 0);
      acc1[c] = __builtin_amdgcn_mfma_f32_16x16x32_bf16(af1, bf, acc1[c], 0, 0, 0);
    }
  }
  const int la0 = rgp * 16 + lk * 4;           // local rows la0..la0+3 and +32
  const float* prow0[4];
  const float* prow1[4];
#pragma unroll
  for (int j = 0; j < 4; ++j) {
    prow0[j] = p + (size_t)((row0 + la0 + j) / CATN) * DD;
    prow1[j] = p + (size_t)((row0 + la0 + 32 + j) / CATN) * DD;
  }
  float sp0[4] = {0.f, 0.f, 0.f, 0.f};
  float sp1[4] = {0.f, 0.f, 0.f, 0.f};
#pragma unroll
  for (int c = 0; c < 13; ++c) {
    int col = (cbeg + c) * 16 + lrow;
    if (col < DD) {
      float bv = bias[col];
#pragma unroll
      for (int j = 0; j < 4; ++j) {
        size_t ra = row0 + la0 + j;
        float v0 = fmaxf(acc0[c][j] + bv, 0.f) + bf2f(A[ra * 416 + col]);
        out2[ra * 416 + col] = f2bf(v0);
        sp0[j] += v0 * prow0[j][col];
        size_t rb = ra + 32;
        float v1 = fmaxf(acc1[c][j] + bv, 0.f) + bf2f(A[rb * 416 + col]);
        out2[rb * 416 + col] = f2bf(v1);
        sp1[j] += v1 * prow1[j][col];
      }
    }
  }
#pragma unroll
  for (int j = 0; j < 4; ++j) {
    sp0[j] += __shfl_xor(sp0[j], 1, 64); sp1[j] += __shfl_xor(sp1[j], 1, 64);
    sp0[j] += __shfl_xor(sp0[j], 2, 64); sp1[j] += __shfl_xor(sp1[j], 2, 64);
    sp0[j] += __shfl_xor(sp0[j], 4, 64); sp1[j] += __shfl_xor(sp1[j], 4, 64);
    sp0[j] += __shfl_xor(sp0[j], 8, 64); sp1[j] += __shfl_xor(sp1[j], 8, 64);
  }
  if (lrow == 0) {
#pragma unroll
    for (int j = 0; j < 4; ++j) {
      ps_sh[la0 + j][nh] = sp0[j];
      ps_sh[la0 + 32 + j][nh] = sp1[j];
    }
  }
  __syncthreads();
  if (tid < 64)
    s_pre[row0 + tid] = (ps_sh[tid][0] + ps_sh[tid][1]) * ATT_INV;
}

// --------- masked softmax over 19 (s_pre precomputed) ; out = sum_c w*intra2
__global__ __launch_bounds__(256) void k_final(const unsigned short* __restrict__ intra2B,
    const float* __restrict__ s_pre, const int* __restrict__ mask,
    float* __restrict__ out) {
  __shared__ float w_sh[CATN];
  const int i = blockIdx.x;
  const int xcd = i & 7, s = i >> 3;
  const int b = 8 * xcd + (s >> 4);
  const int n = s & 15;
  const int bn = b * 16 + n;
  const int tid = threadIdx.x;
  if (tid == 0) {
    float sv[CATN];
    float mx = -3.4e38f;
#pragma unroll
    for (int c = 0; c < CATN; ++c) {
      bool mk = (c == CATN - 1) || (mask[b * CATN + c] != 0);
      float sc = mk ? s_pre[bn * CATN + c] : -3.4e38f;
      sv[c] = sc;
      mx = fmaxf(mx, sc);
    }
    float den = 0.f;
#pragma unroll
    for (int c = 0; c < CATN; ++c) {
      float e = (sv[c] <= -3.3e38f) ? 0.f : expf(sv[c] - mx);
      w_sh[c] = e;
      den += e;
    }
    float inv = 1.0f / den;
#pragma unroll
    for (int c = 0; c < CATN; ++c) w_sh[c] *= inv;
  }
  __syncthreads();
  const unsigned short* ib = intra2B + (size_t)bn * CATN * 416;
  for (int d = tid; d < DD; d += 256) {
    float o = 0.f;
#pragma unroll
    for (int c = 0; c < CATN; ++c) o += w_sh[c] * bf2f(ib[c * 416 + d]);
    out[(size_t)bn * DD + d] = o;
  }
}

// ============================================================================
extern "C" void kernel_launch(void* const* d_in, const int* in_sizes, int n_in,
                              void* d_out, int out_size, void* d_ws, size_t ws_size,
                              hipStream_t stream) {
  const float* hist  = (const float*)d_in[0];
  const float* cand  = (const float*)d_in[1];
  const float* G     = (const float*)d_in[2];
  const int*   cmask = (const int*)d_in[3];
  const int*   cidx  = (const int*)d_in[4];
  const float* proxy = (const float*)d_in[5];
  const float* gW    = (const float*)d_in[6];
  const float* gb    = (const float*)d_in[7];
  const float* lns   = (const float*)d_in[8];
  const float* lnb   = (const float*)d_in[9];
  const float* Kw    = (const float*)d_in[10];
  const float* Qw    = (const float*)d_in[11];
  const float* Qbb   = (const float*)d_in[12];
  const float* afW   = (const float*)d_in[13];
  const float* afb   = (const float*)d_in[14];
  const float* icKw  = (const float*)d_in[15];
  const float* icQw  = (const float*)d_in[16];
  const float* icQb  = (const float*)d_in[17];
  float* out = (float*)d_out;
  float* ws  = (float*)d_ws;

  // ---- workspace layout (float offsets) ----
  // he      @0          3,020,800  (-> Pbuf/qbuf/pbuf/s_pre after toT_gf)
  // s1      @3,020,800  3,020,800  (h1/h2 -> Kbuf)
  // s2f     @6,041,600  3,020,800  (tmpb bf16 [7552][416] -> gf fp32 [6400][400])
  // TB      @9,062,400  1,703,936  ([64][416][128] bf16)
  // intraB  @10,766,336 4,046,848  (bf16 [19456][416])
  // intra2B @14,813,184 4,046,848  (bf16 [19456][416])
  // wbase   @18,860,032   525,824 ; bias3 @19,385,856 (608)
  float* he    = ws;
  float* s1    = ws + 3020800;
  float* s2f   = ws + 6041600;
  unsigned short* tmpb   = (unsigned short*)(ws + 6041600);
  unsigned short* TB     = (unsigned short*)(ws + 9062400);
  unsigned short* intraB = (unsigned short*)(ws + 10766336);
  unsigned short* intra2B= (unsigned short*)(ws + 14813184);
  unsigned short* wbase  = (unsigned short*)(ws + 18860032);
  float* bias3 = ws + 19385856;
  unsigned short* Pbuf = (unsigned short*)ws;
  float* qbuf  = ws + 1310720;                  // [1024][200]
  float* pbuf  = ws + 1515520;                  // [1024][400]
  float* s_pre = ws + 1925120;                  // [19456]
  float* Kbuf  = s1;
  unsigned short* gW0t  = wbase;
  unsigned short* gW1t  = wbase + 173056;
  unsigned short* afWt  = wbase + 346112;
  unsigned short* Kwt   = wbase + 519168;       // [224][416]
  unsigned short* icKwB = wbase + 612352;       // [416][224]
  unsigned short* icQwB = wbase + 705536;       // [416][224]
  unsigned short* Wqp   = wbase + 798720;       // [608][416]

  // 0. weight prep + fused icQ->p matrix
  k_prep_all<<<3461, 256, 0, stream>>>(gW, afW, Kw, Qw, icQw, icKw, Qbb, icQb, wbase, bias3);
  k_prep_M<<<13, 256, 0, stream>>>(icKwB, icQwB, Wqp);
  // 1. fused concat + transpose: he + hT
  k_toT_he<<<448, 256, 0, stream>>>(hist, proxy, he, TB);
  // 2-3. GCN layer 0
  k_gmm<<<256, 256, 0, stream>>>(G, TB, tmpb);
  k_mgb_ln<<<BN / 32, 256, 0, stream>>>(tmpb, gW0t, gb, he, lns, lnb, s1);
  // 4-6. GCN layer 1 (in-place s1)
  k_toT<NODES><<<448, 256, 0, stream>>>(s1, TB);
  k_gmm<<<256, 256, 0, stream>>>(G, TB, tmpb);
  k_mgb_ln<<<BN / 32, 256, 0, stream>>>(tmpb, gW1t, gb + DD, s1, lns + DD, lnb + DD, s1);
  // 7. fused gf = (h2+he)[:, :HH] + transpose: gf + gfT
  k_toT_gf<<<448, 256, 0, stream>>>(s1, he, s2f, TB);
  // 8. K = gf @ Kw -> Kbuf (grid 200 %8==0)
  k_mg<400, 416, 200, 0><<<BH / 32, 256, 0, stream>>>(s2f, Kwt, nullptr, Kbuf, nullptr);
  // 9. fused Q-proj + p-proj (grid 32 %8==0)
  k_mg<400, 416, 608, 6><<<BB * NN / 32, 256, 0, stream>>>(cand, Wqp, bias3, qbuf, pbuf);
  // 10. alpha -> P (b-chunked XCD)
  k_palpha<<<BB * NN, 256, 0, stream>>>(Kbuf, qbuf, cidx, Pbuf);
  // 11. intra = P @ gf -> intraB bf16 (b-chunked XCD)
  k_sc<<<BB * CATN, 128, 0, stream>>>(Pbuf, TB, intraB);
  // 12. affine v3 (64-row, dual-rg B reuse) + fused s-dot -> intra2B, s_pre
  k_af64<<<BB * NN * CATN / 64, 256, 0, stream>>>(intraB, afWt, afb, pbuf, s_pre, intra2B);
  // 13. final softmax + weighted sum (b-chunked XCD)
  k_final<<<BB * NN, 256, 0, stream>>>(intra2B, s_pre, cmask, out);
}